// Round 16
// baseline (261.022 us; speedup 1.0000x reference)
//
#include <hip/hip_runtime.h>
#include <hip/hip_bf16.h>
#include <cstddef>
#include <cstdint>

constexpr int cB = 8, cN = 8192, cM = 2048, cK = 16, cC = 128, cH = 64, cO = 256, cCH = 192;
constexpr int NPTS = cB * cM;        // 16384
constexpr float cEPS = 1e-5f;

typedef __attribute__((ext_vector_type(8))) short short8;
typedef __attribute__((ext_vector_type(4))) float f32x4;

// ---- workspace layout (float offsets) ----
constexpr size_t ACC_BN1 = 0, ACC_BN2 = 128, ACC_STEM = 256, ACC_X1 = 768, ACC_X2 = 1280, ACC_FIN = 1792;
constexpr size_t OFF_SFT = 8192;                                   // s_feats packed u32(bf16 c, c+64) [B,N,64]
constexpr size_t OFF_H2  = OFF_SFT + (size_t)cB * cN * 64;         // h2 bf16 [pt][64o][16k]
constexpr size_t OFF_TST = OFF_H2 + (size_t)NPTS * 512;            // stem post-ELU bf16 [pt][256]
constexpr size_t OFF_Y1  = OFF_TST + (size_t)NPTS * 128;           // y1 post-ELU bf16 [pt][256]; later DW bf16
constexpr size_t OFF_Y2  = OFF_Y1 + (size_t)NPTS * 256;            // y2 post-ELU bf16 [pt][256]
constexpr size_t OFF_AL  = OFF_Y2 + (size_t)NPTS * 128;            // aligned coords f32 [pt][48]
constexpr size_t OFF_DW  = OFF_Y1;
constexpr size_t WS_FLOATS = OFF_Y2 + (size_t)NPTS * 256;          // 92.3 MB

__device__ __forceinline__ float eluf(float x) { return x > 0.f ? x : __expf(x) - 1.f; }

__device__ __forceinline__ uint32_t pk2bf(float a, float b) {
    uint32_t ua = __float_as_uint(a); ua += 0x7FFFu + ((ua >> 16) & 1u);
    uint32_t ub = __float_as_uint(b); ub += 0x7FFFu + ((ub >> 16) & 1u);
    return (ua >> 16) | (ub & 0xFFFF0000u);
}
__device__ __forceinline__ float bf_lo(uint32_t u) { return __uint_as_float(u << 16); }
__device__ __forceinline__ float bf_hi(uint32_t u) { return __uint_as_float(u & 0xFFFF0000u); }
__device__ __forceinline__ uint16_t f2bf_u(float a) {
    uint32_t ua = __float_as_uint(a); ua += 0x7FFFu + ((ua >> 16) & 1u);
    return (uint16_t)(ua >> 16);
}

#define WAVE_SYNC() do { asm volatile("s_waitcnt lgkmcnt(0)" ::: "memory"); \
                         __builtin_amdgcn_sched_barrier(0); } while (0)

// ==== kAT: j%5==0 -> kA (id=j/5); else -> k_tr (id=j-j/5-1). ====
__global__ __launch_bounds__(256) void kAT(const float* __restrict__ qp, const float* __restrict__ sp,
        const float* __restrict__ f1w, const float* __restrict__ f1b,
        const float* __restrict__ stw, const float* __restrict__ stb,
        const float* __restrict__ sf, const int* __restrict__ nidx, float* __restrict__ ws) {
    __shared__ __align__(16) unsigned char smem[15872];
    int t = threadIdx.x;
    int j = blockIdx.x;
    if (j % 5 != 0) {
        float* tA = (float*)smem;               // [32][33]
        float* tB = (float*)(smem + 4224);      // [32][33]
        int id = j - j / 5 - 1;
        int n0 = (id & 255) * 32, c0 = ((id >> 8) & 1) * 32, b = id >> 9;
        int tx = t & 31, ty = t >> 5;
        #pragma unroll
        for (int jj = 0; jj < 32; jj += 8) {
            tA[(ty + jj)*33 + tx] = sf[((size_t)b * cC + (c0 + ty + jj)) * cN + n0 + tx];
            tB[(ty + jj)*33 + tx] = sf[((size_t)b * cC + 64 + (c0 + ty + jj)) * cN + n0 + tx];
        }
        __syncthreads();
        uint32_t* outp = (uint32_t*)(ws + OFF_SFT);
        #pragma unroll
        for (int jj = 0; jj < 32; jj += 8)
            outp[((size_t)b * cN + (n0 + ty + jj)) * 64 + c0 + tx] =
                pk2bf(tA[tx*33 + ty + jj], tB[tx*33 + ty + jj]);
        return;
    }
    int kaid = j / 5;
    float (*alw)[4][48]   = (float(*)[4][48])smem;             // 3072B
    uint16_t (*albs)[64]  = (uint16_t(*)[64])(smem + 3072);    // 2048B
    uint16_t (*tstt)[256] = (uint16_t(*)[256])(smem + 5120);   // 8192B
    float* red            = (float*)(smem + 13312);            // 640 fl
    int lane = t & 63, w = t >> 6;
    int ncol = lane & 15, g = lane >> 4;
    for (int l = t; l < 640; l += 256) red[l] = 0.f;
    __syncthreads();
    short8 bfr[4][2];
    float sbias[4];
    #pragma unroll
    for (int tt = 0; tt < 4; tt++) {
        int o = w*64 + tt*16 + ncol;
        sbias[tt] = stb[o];
        #pragma unroll
        for (int s = 0; s < 2; s++) {
            short8 bb;
            #pragma unroll
            for (int jj = 0; jj < 8; jj++) {
                int Kk = s*32 + g*8 + jj;
                bb[jj] = (Kk < 48) ? (short)f2bf_u(stw[(size_t)o*48 + Kk]) : (short)0;
            }
            bfr[tt][s] = bb;
        }
    }
    float w0 = f1w[lane*3], w1 = f1w[lane*3+1], w2 = f1w[lane*3+2], fb = f1b[lane];
    int pt0 = kaid * 16;
    {
        int p = lane >> 4, k = lane & 15;
        int row = w*4 + p;
        int pt = pt0 + row, b = pt >> 11, m = pt & (cM - 1);
        int id = nidx[(size_t)pt * cK + k];
        #pragma unroll
        for (int c = 0; c < 3; c++) {
            float v = sp[((size_t)b*3 + c)*cN + id] - qp[((size_t)b*3 + c)*cM + m];
            alw[w][p][c*16 + k] = v;
            int bo = ((c*16 + k)*2) ^ ((row & 7) << 4);
            *(uint16_t*)((char*)&albs[row][0] + bo) = f2bf_u(v);
        }
        int bo = ((48 + k)*2) ^ ((row & 7) << 4);
        *(uint16_t*)((char*)&albs[row][0] + bo) = 0;
    }
    WAVE_SYNC();
    {
        float* alg = ws + OFF_AL;
        const float* srcA = &alw[w][0][0];
        int ptw = pt0 + w*4;
        #pragma unroll
        for (int i = 0; i < 3; i++)
            alg[(size_t)ptw*48 + i*64 + lane] = srcA[i*64 + lane];
    }
    float ps1 = 0, pss1 = 0;
    #pragma unroll
    for (int p = 0; p < 4; p++) {
        #pragma unroll
        for (int k = 0; k < 16; k++) {
            float a0 = alw[w][p][k], a1 = alw[w][p][16 + k], a2 = alw[w][p][32 + k];
            float e = eluf(fb + w0*a0 + w1*a1 + w2*a2);
            ps1 += e; pss1 += e*e;
        }
    }
    atomicAdd(&red[512 + lane], ps1); atomicAdd(&red[576 + lane], pss1);
    __syncthreads();
    short8 a0, a1;
    {
        int b0 = (g*16) ^ ((ncol & 7) << 4);
        int b1 = (64 + g*16) ^ ((ncol & 7) << 4);
        a0 = *(const short8*)((const char*)&albs[ncol][0] + b0);
        a1 = *(const short8*)((const char*)&albs[ncol][0] + b1);
    }
    #pragma unroll
    for (int tt = 0; tt < 4; tt++) {
        f32x4 acc = {0.f, 0.f, 0.f, 0.f};
        acc = __builtin_amdgcn_mfma_f32_16x16x32_bf16(a0, bfr[tt][0], acc, 0, 0, 0);
        acc = __builtin_amdgcn_mfma_f32_16x16x32_bf16(a1, bfr[tt][1], acc, 0, 0, 0);
        int o = w*64 + tt*16 + ncol;
        float ps2 = 0, pss2 = 0;
        #pragma unroll
        for (int r = 0; r < 4; r++) {
            float e = eluf(acc[r] + sbias[tt]);
            ps2 += e; pss2 += e*e;
            tstt[g*4 + r][o] = f2bf_u(e);
        }
        atomicAdd(&red[o], ps2); atomicAdd(&red[256 + o], pss2);
    }
    __syncthreads();
    {
        uint4* tst4 = (uint4*)(ws + OFF_TST);
        const uint4* srcT = (const uint4*)&tstt[0][0];
        tst4[(size_t)pt0*32 + t]       = srcT[t];
        tst4[(size_t)pt0*32 + 256 + t] = srcT[256 + t];
    }
    atomicAdd(&ws[ACC_STEM + t], red[t]);
    atomicAdd(&ws[ACC_STEM + 256 + t], red[256 + t]);
    if (t < 64) { atomicAdd(&ws[ACC_BN1 + t], red[512 + t]); atomicAdd(&ws[ACC_BN1 + 64 + t], red[576 + t]); }
}

// ==== kCE v4: 8 pts/block (2 per wave), 4096 blocks interleaved even=kC odd=kE.
//      Union LDS 27.6KB -> 5 blocks/CU (was 4) + finer drain granularity. ====
__global__ __launch_bounds__(256) void kCE(const float* __restrict__ f1w, const float* __restrict__ f1b,
        const float* __restrict__ f2w, const float* __restrict__ f2b,
        const float* __restrict__ f1g, const float* __restrict__ f1be,
        const float* __restrict__ x1w, const float* __restrict__ x1b,
        const float* __restrict__ stg, const float* __restrict__ stbe, float* __restrict__ ws) {
    __shared__ __align__(16) unsigned char smem[27648];
    int t = threadIdx.x, lane = t & 63, w = t >> 6;
    int j = blockIdx.x;
    if ((j & 1) == 0) {
        // ---- kC part: 2 pts/wave ----
        int kcid = j >> 1;
        float (*alw)[2][48] = (float(*)[2][48])smem;                      // 1536B
        unsigned char (*h1l)[2][2048] = (unsigned char(*)[2][2048])(smem + 1536);  // 16384B
        float* s1s  = (float*)(smem + 17920);
        float* sh1s = (float*)(smem + 18176);
        float* b2s  = (float*)(smem + 18432);
        float* red  = (float*)(smem + 18688);   // 128 fl
        if (t < 128) red[t] = 0.f;
        if (t < 64) {
            float mn = ws[ACC_BN1 + t] * (1.f/262144.f);
            float vr = ws[ACC_BN1 + 64 + t] * (1.f/262144.f) - mn*mn;
            float s = f1g[t] * rsqrtf(vr + cEPS);
            s1s[t] = s; sh1s[t] = f1be[t] - mn*s;
        }
        __syncthreads();
        float w0 = f1w[lane*3], w1 = f1w[lane*3+1], w2 = f1w[lane*3+2], fb = f1b[lane];
        int ncol = lane & 15, g = lane >> 4;
        if (t < 64) {
            float a = f2b[t];
            const float* fr = f2w + (size_t)t*64;
            #pragma unroll 8
            for (int c = 0; c < 64; c++) a += fr[c] * sh1s[c];
            b2s[t] = a;
        }
        short8 bfr[4][2];
        #pragma unroll
        for (int tt = 0; tt < 4; tt++) {
            int o = tt*16 + ncol;
            #pragma unroll
            for (int s = 0; s < 2; s++) {
                short8 bb;
                #pragma unroll
                for (int jj = 0; jj < 8; jj++) {
                    int c = s*32 + g*8 + jj;
                    bb[jj] = (short)f2bf_u(f2w[(size_t)o*64 + c] * s1s[c]);
                }
                bfr[tt][s] = bb;
            }
        }
        __syncthreads();
        float bias2[4];
        #pragma unroll
        for (int tt = 0; tt < 4; tt++) bias2[tt] = b2s[tt*16 + ncol];
        int ptw = kcid * 8 + w * 2;
        {
            const float* alg = ws + OFF_AL;
            float* dst = &alw[w][0][0];
            dst[lane] = alg[(size_t)ptw*48 + lane];
            if (lane < 32) dst[64 + lane] = alg[(size_t)ptw*48 + 64 + lane];
        }
        WAVE_SYNC();
        #pragma unroll
        for (int p = 0; p < 2; p++) {
            #pragma unroll
            for (int k = 0; k < 16; k++) {
                float a0 = alw[w][p][k], a1 = alw[w][p][16 + k], a2 = alw[w][p][32 + k];
                float e = eluf(fb + w0*a0 + w1*a1 + w2*a2);
                int byteoff = (lane*2) ^ ((k & 7) << 4);
                *(uint16_t*)&h1l[w][p][k*128 + byteoff] = (uint16_t)f2bf_u(e);
            }
        }
        WAVE_SYNC();
        float ps[4] = {0,0,0,0}, pss[4] = {0,0,0,0};
        int b0o = (g*16) ^ ((ncol & 7) << 4);
        int b1o = (64 + g*16) ^ ((ncol & 7) << 4);
        short8 a0v[2], a1v[2];
        #pragma unroll
        for (int p = 0; p < 2; p++) {
            a0v[p] = *(const short8*)&h1l[w][p][ncol*128 + b0o];
            a1v[p] = *(const short8*)&h1l[w][p][ncol*128 + b1o];
        }
        WAVE_SYNC();
        uint32_t* h2p = (uint32_t*)(ws + OFF_H2);
        #pragma unroll
        for (int p = 0; p < 2; p++) {
            int pt = ptw + p;
            #pragma unroll
            for (int tt = 0; tt < 4; tt++) {
                f32x4 acc = {0.f, 0.f, 0.f, 0.f};
                acc = __builtin_amdgcn_mfma_f32_16x16x32_bf16(a0v[p], bfr[tt][0], acc, 0, 0, 0);
                acc = __builtin_amdgcn_mfma_f32_16x16x32_bf16(a1v[p], bfr[tt][1], acc, 0, 0, 0);
                float e0 = eluf(acc[0] + bias2[tt]);
                float e1 = eluf(acc[1] + bias2[tt]);
                float e2 = eluf(acc[2] + bias2[tt]);
                float e3 = eluf(acc[3] + bias2[tt]);
                ps[tt]  += e0+e1+e2+e3;
                pss[tt] += e0*e0+e1*e1+e2*e2+e3*e3;
                int o = tt*16 + ncol;
                *(uint2*)(h2p + (size_t)pt*512 + o*8 + g*2) = make_uint2(pk2bf(e0, e1), pk2bf(e2, e3));
            }
        }
        #pragma unroll
        for (int tt = 0; tt < 4; tt++) {
            int o = tt*16 + ncol;
            atomicAdd(&red[o], ps[tt]); atomicAdd(&red[64 + o], pss[tt]);
        }
        __syncthreads();
        if (t < 64) { atomicAdd(&ws[ACC_BN2 + t], red[t]); atomicAdd(&ws[ACC_BN2 + 64 + t], red[64 + t]); }
        return;
    }
    // ---- kE part: 2 pts/wave ----
    {
        int keid = j >> 1;
        float* xw = (float*)smem;                                 // 17408B
        float (*ts)[2][256] = (float(*)[2][256])(smem + 17408);   // 8192B
        float* red = (float*)(smem + 25600);                      // 2048B
        for (int l = t; l < 4096; l += 256) xw[(l >> 4)*17 + (l & 15)] = x1w[l];
        for (int l = t; l < 512; l += 256) red[l] = 0.f;
        float sscl[4], sshf[4];
        #pragma unroll
        for (int i = 0; i < 4; i++) {
            int ch = lane*4 + i;
            float mn = ws[ACC_STEM + ch] * (1.f/16384.f);
            float vr = ws[ACC_STEM + 256 + ch] * (1.f/16384.f) - mn*mn;
            float s = stg[ch] * rsqrtf(vr + cEPS);
            sscl[i] = s; sshf[i] = stbe[ch] - mn*s;
        }
        __syncthreads();
        const uint16_t* tstb = (const uint16_t*)(ws + OFF_TST);
        int pt0 = keid * 8 + w * 2;
        #pragma unroll
        for (int p = 0; p < 2; p++) {
            uint2 v2 = *(const uint2*)&tstb[(size_t)(pt0 + p)*256 + lane*4];
            ts[w][p][lane*4+0] = sscl[0]*bf_lo(v2.x) + sshf[0];
            ts[w][p][lane*4+1] = sscl[1]*bf_hi(v2.x) + sshf[1];
            ts[w][p][lane*4+2] = sscl[2]*bf_lo(v2.y) + sshf[2];
            ts[w][p][lane*4+3] = sscl[3]*bf_hi(v2.y) + sshf[3];
        }
        WAVE_SYNC();
        float eo[2][4];
        #pragma unroll
        for (int sl = 0; sl < 4; sl++) {
            int o = (sl < 2) ? (lane*2 + sl) : (128 + lane*2 + sl - 2);
            int gg = o >> 4;
            float bia = x1b[o];
            float a0 = bia, a1 = bia;
            #pragma unroll
            for (int j4 = 0; j4 < 4; j4++) {
                float s0 = xw[o*17 + j4*4], s1 = xw[o*17 + j4*4+1], s2 = xw[o*17 + j4*4+2], s3 = xw[o*17 + j4*4+3];
                float4 t0 = *(const float4*)&ts[w][0][gg*16 + j4*4];
                float4 t1 = *(const float4*)&ts[w][1][gg*16 + j4*4];
                a0 += s0*t0.x + s1*t0.y + s2*t0.z + s3*t0.w;
                a1 += s0*t1.x + s1*t1.y + s2*t1.z + s3*t1.w;
            }
            eo[0][sl] = eluf(a0); eo[1][sl] = eluf(a1);
            float ps = eo[0][sl] + eo[1][sl];
            float qs = eo[0][sl]*eo[0][sl] + eo[1][sl]*eo[1][sl];
            atomicAdd(&red[o], ps); atomicAdd(&red[256 + o], qs);
        }
        uint32_t* y1p = (uint32_t*)(ws + OFF_Y1);
        #pragma unroll
        for (int p = 0; p < 2; p++) {
            y1p[(size_t)(pt0 + p)*128 + lane]      = pk2bf(eo[p][0], eo[p][1]);
            y1p[(size_t)(pt0 + p)*128 + 64 + lane] = pk2bf(eo[p][2], eo[p][3]);
        }
        __syncthreads();
        atomicAdd(&ws[ACC_X1 + t], red[t]); atomicAdd(&ws[ACC_X1 + 256 + t], red[256 + t]);
    }
}

// ---- kG: y1 bf16 (BN_x1 inline, transposed stage) -> grouped conv x2 -> y2 bf16 + x2 stats ----
__global__ __launch_bounds__(256) void kG(const float* __restrict__ x2w, const float* __restrict__ x2b,
        const float* __restrict__ x1g, const float* __restrict__ x1be, float* __restrict__ ws) {
    __shared__ float xw[256 * 17];
    __shared__ float ts[4][4][256];
    __shared__ float red[512];
    int t = threadIdx.x, lane = t & 63, w = t >> 6;
    for (int l = t; l < 4096; l += 256) xw[(l >> 4)*17 + (l & 15)] = x2w[l];
    for (int l = t; l < 512; l += 256) red[l] = 0.f;
    float sscl[4], sshf[4];
    #pragma unroll
    for (int i = 0; i < 4; i++) {
        int ch = lane*4 + i;
        float mn = ws[ACC_X1 + ch] * (1.f/16384.f);
        float vr = ws[ACC_X1 + 256 + ch] * (1.f/16384.f) - mn*mn;
        float s = x1g[ch] * rsqrtf(vr + cEPS);
        sscl[i] = s; sshf[i] = x1be[ch] - mn*s;
    }
    __syncthreads();
    const uint32_t* y1p = (const uint32_t*)(ws + OFF_Y1);
    int pt0 = blockIdx.x * 16 + w * 4;
    #pragma unroll
    for (int p = 0; p < 4; p++) {
        uint2 v2 = *(const uint2*)(y1p + (size_t)(pt0 + p)*128 + lane*2);
        float vv[4] = { sscl[0]*bf_lo(v2.x) + sshf[0], sscl[1]*bf_hi(v2.x) + sshf[1],
                        sscl[2]*bf_lo(v2.y) + sshf[2], sscl[3]*bf_hi(v2.y) + sshf[3] };
        #pragma unroll
        for (int i = 0; i < 4; i++) {
            int ch = lane*4 + i;
            ts[w][p][((ch & 15) << 4) | (ch >> 4)] = vv[i];
        }
    }
    WAVE_SYNC();
    float eo[4][4];
    #pragma unroll
    for (int sl = 0; sl < 4; sl++) {
        int o = (sl < 2) ? (lane*2 + sl) : (128 + lane*2 + sl - 2);
        int gg = o >> 4;
        float bia = x2b[o];
        float a0 = bia, a1 = bia, a2 = bia, a3 = bia;
        #pragma unroll
        for (int j4 = 0; j4 < 4; j4++) {
            float s0 = xw[o*17 + j4*4], s1 = xw[o*17 + j4*4+1], s2 = xw[o*17 + j4*4+2], s3 = xw[o*17 + j4*4+3];
            float4 t0 = *(const float4*)&ts[w][0][gg*16 + j4*4];
            float4 t1 = *(const float4*)&ts[w][1][gg*16 + j4*4];
            float4 t2 = *(const float4*)&ts[w][2][gg*16 + j4*4];
            float4 t3 = *(const float4*)&ts[w][3][gg*16 + j4*4];
            a0 += s0*t0.x + s1*t0.y + s2*t0.z + s3*t0.w;
            a1 += s0*t1.x + s1*t1.y + s2*t1.z + s3*t1.w;
            a2 += s0*t2.x + s1*t2.y + s2*t2.z + s3*t2.w;
            a3 += s0*t3.x + s1*t3.y + s2*t3.z + s3*t3.w;
        }
        eo[0][sl] = eluf(a0); eo[1][sl] = eluf(a1); eo[2][sl] = eluf(a2); eo[3][sl] = eluf(a3);
        float ps = eo[0][sl]+eo[1][sl]+eo[2][sl]+eo[3][sl];
        float qs = eo[0][sl]*eo[0][sl]+eo[1][sl]*eo[1][sl]+eo[2][sl]*eo[2][sl]+eo[3][sl]*eo[3][sl];
        atomicAdd(&red[o], ps); atomicAdd(&red[256 + o], qs);
    }
    uint32_t* y2p = (uint32_t*)(ws + OFF_Y2);
    #pragma unroll
    for (int p = 0; p < 4; p++) {
        y2p[(size_t)(pt0 + p)*128 + lane]      = pk2bf(eo[p][0], eo[p][1]);
        y2p[(size_t)(pt0 + p)*128 + 64 + lane] = pk2bf(eo[p][2], eo[p][3]);
    }
    __syncthreads();
    atomicAdd(&ws[ACC_X2 + t], red[t]); atomicAdd(&ws[ACC_X2 + 256 + t], red[256 + t]);
}

// ---- kI: wave-per-point gather (packed SFT) + qf + depthwise -> dw (bf16) ----
__global__ __launch_bounds__(256) void kI(const float* __restrict__ dww,
        const float* __restrict__ f2g, const float* __restrict__ f2be,
        const float* __restrict__ x2g, const float* __restrict__ x2be,
        const int* __restrict__ nidx, float* __restrict__ ws) {
    __shared__ float dws[192 * 17];
    __shared__ float xs[4][256];
    const uint32_t* h2p = (const uint32_t*)(ws + OFF_H2);
    const uint32_t* sfp = (const uint32_t*)(ws + OFF_SFT);
    const uint32_t* y2p = (const uint32_t*)(ws + OFF_Y2);
    int t = threadIdx.x, lane = t & 63, w = t >> 6;
    for (int l = t; l < 3072; l += 256) dws[(l >> 4)*17 + (l & 15)] = dww[l];
    float sx[4], shx[4];
    #pragma unroll
    for (int i = 0; i < 4; i++) {
        int ch = lane*4 + i;
        float mn = ws[ACC_X2 + ch] * (1.f/16384.f);
        float vr = ws[ACC_X2 + 256 + ch] * (1.f/16384.f) - mn*mn;
        float s = x2g[ch] * rsqrtf(vr + cEPS);
        sx[i] = s; shx[i] = x2be[ch] - mn*s;
    }
    float s2, sh2;
    {
        float mn = ws[ACC_BN2 + lane] * (1.f/262144.f);
        float vr = ws[ACC_BN2 + 64 + lane] * (1.f/262144.f) - mn*mn;
        s2 = f2g[lane] * rsqrtf(vr + cEPS);
        sh2 = f2be[lane] - mn*s2;
    }
    __syncthreads();
    uint16_t* dwb = (uint16_t*)(ws + OFF_DW);
    int pt0 = blockIdx.x * 8 + w * 2;
    for (int p = 0; p < 2; p++) {
        int pt = pt0 + p, b = pt >> 11;
        const int4* ip = (const int4*)(nidx + (size_t)pt * cK);
        int4 iA = ip[0], iB = ip[1], iC2 = ip[2], iD = ip[3];
        int idxv[16] = {iA.x, iA.y, iA.z, iA.w, iB.x, iB.y, iB.z, iB.w,
                        iC2.x, iC2.y, iC2.z, iC2.w, iD.x, iD.y, iD.z, iD.w};
        float nfa[16], nfb[16];
        #pragma unroll
        for (int k = 0; k < 16; k++) {
            uint32_t u = sfp[((size_t)b*cN + idxv[k]) * 64 + lane];
            nfa[k] = bf_lo(u); nfb[k] = bf_hi(u);
        }
        float nfh[16];
        {
            const uint4* srcq = (const uint4*)(h2p + (size_t)pt*512 + lane*8);
            uint4 ha = srcq[0], hbq = srcq[1];
            nfh[0]  = s2*bf_lo(ha.x)  + sh2; nfh[1]  = s2*bf_hi(ha.x)  + sh2;
            nfh[2]  = s2*bf_lo(ha.y)  + sh2; nfh[3]  = s2*bf_hi(ha.y)  + sh2;
            nfh[4]  = s2*bf_lo(ha.z)  + sh2; nfh[5]  = s2*bf_hi(ha.z)  + sh2;
            nfh[6]  = s2*bf_lo(ha.w)  + sh2; nfh[7]  = s2*bf_hi(ha.w)  + sh2;
            nfh[8]  = s2*bf_lo(hbq.x) + sh2; nfh[9]  = s2*bf_hi(hbq.x) + sh2;
            nfh[10] = s2*bf_lo(hbq.y) + sh2; nfh[11] = s2*bf_hi(hbq.y) + sh2;
            nfh[12] = s2*bf_lo(hbq.z) + sh2; nfh[13] = s2*bf_hi(hbq.z) + sh2;
            nfh[14] = s2*bf_lo(hbq.w) + sh2; nfh[15] = s2*bf_hi(hbq.w) + sh2;
        }
        {
            uint2 v2 = *(const uint2*)(y2p + (size_t)pt*128 + lane*2);
            xs[w][lane*4+0] = sx[0]*bf_lo(v2.x) + shx[0];
            xs[w][lane*4+1] = sx[1]*bf_hi(v2.x) + shx[1];
            xs[w][lane*4+2] = sx[2]*bf_lo(v2.y) + shx[2];
            xs[w][lane*4+3] = sx[3]*bf_hi(v2.y) + shx[3];
        }
        WAVE_SYNC();
        float qc[16];
        #pragma unroll
        for (int l = 0; l < 16; l++) qc[l] = 0.f;
        #pragma unroll
        for (int k = 0; k < 16; k++) {
            float4 x0 = *(const float4*)&xs[w][k*16 + 0];
            float4 x1 = *(const float4*)&xs[w][k*16 + 4];
            float4 x2v = *(const float4*)&xs[w][k*16 + 8];
            float4 x3 = *(const float4*)&xs[w][k*16 + 12];
            float nh = nfh[k];
            qc[0] += nh*x0.x; qc[1] += nh*x0.y; qc[2]  += nh*x0.z; qc[3]  += nh*x0.w;
            qc[4] += nh*x1.x; qc[5] += nh*x1.y; qc[6]  += nh*x1.z; qc[7]  += nh*x1.w;
            qc[8] += nh*x2v.x; qc[9] += nh*x2v.y; qc[10] += nh*x2v.z; qc[11] += nh*x2v.w;
            qc[12] += nh*x3.x; qc[13] += nh*x3.y; qc[14] += nh*x3.z; qc[15] += nh*x3.w;
        }
        float dc = 0;
        #pragma unroll
        for (int l = 0; l < 16; l++) dc += qc[l] * dws[(lane + 128)*17 + l];
        float qa[16], qb[16];
        #pragma unroll
        for (int l = 0; l < 16; l++) { qa[l] = 0.f; qb[l] = 0.f; }
        #pragma unroll
        for (int k = 0; k < 16; k++) {
            float4 x0 = *(const float4*)&xs[w][k*16 + 0];
            float4 x1 = *(const float4*)&xs[w][k*16 + 4];
            float4 x2v = *(const float4*)&xs[w][k*16 + 8];
            float4 x3 = *(const float4*)&xs[w][k*16 + 12];
            float na = nfa[k], nb = nfb[k];
            qa[0] += na*x0.x; qa[1] += na*x0.y; qa[2]  += na*x0.z; qa[3]  += na*x0.w;
            qa[4] += na*x1.x; qa[5] += na*x1.y; qa[6]  += na*x1.z; qa[7]  += na*x1.w;
            qa[8] += na*x2v.x; qa[9] += na*x2v.y; qa[10] += na*x2v.z; qa[11] += na*x2v.w;
            qa[12] += na*x3.x; qa[13] += na*x3.y; qa[14] += na*x3.z; qa[15] += na*x3.w;
            qb[0] += nb*x0.x; qb[1] += nb*x0.y; qb[2]  += nb*x0.z; qb[3]  += nb*x0.w;
            qb[4] += nb*x1.x; qb[5] += nb*x1.y; qb[6]  += nb*x1.z; qb[7]  += nb*x1.w;
            qb[8] += nb*x2v.x; qb[9] += nb*x2v.y; qb[10] += nb*x2v.z; qb[11] += nb*x2v.w;
            qb[12] += nb*x3.x; qb[13] += nb*x3.y; qb[14] += nb*x3.z; qb[15] += nb*x3.w;
        }
        float da = 0, db = 0;
        #pragma unroll
        for (int l = 0; l < 16; l++) {
            da += qa[l] * dws[lane*17 + l];
            db += qb[l] * dws[(lane + 64)*17 + l];
        }
        uint16_t* op = dwb + (size_t)pt * cCH;
        op[lane] = f2bf_u(da); op[lane + 64] = f2bf_u(db); op[lane + 128] = f2bf_u(dc);
        WAVE_SYNC();
    }
}

// ---- kJ: MFMA GEMM out[o][m] = pww[o][c] . dw[m][c] + bias, ELU, stats ----
__global__ __launch_bounds__(256) void kJ(const float* __restrict__ pww, const float* __restrict__ pwb,
                                          float* __restrict__ ws, float* __restrict__ out) {
    __shared__ float red[128];
    int t = threadIdx.x, lane = t & 63, w = t >> 6;
    int ncol = lane & 15, g = lane >> 4;
    if (t < 128) red[t] = 0.f;
    __syncthreads();
    int p0 = blockIdx.x * 64;
    int otile = blockIdx.y * 64 + w * 16;
    short8 afr[6];
    #pragma unroll
    for (int kt = 0; kt < 6; kt++) {
        const float* src = pww + (size_t)(otile + ncol) * cCH + kt*32 + g*8;
        float4 v0 = *(const float4*)src;
        float4 v1 = *(const float4*)(src + 4);
        short8 aa;
        aa[0] = (short)f2bf_u(v0.x); aa[1] = (short)f2bf_u(v0.y);
        aa[2] = (short)f2bf_u(v0.z); aa[3] = (short)f2bf_u(v0.w);
        aa[4] = (short)f2bf_u(v1.x); aa[5] = (short)f2bf_u(v1.y);
        aa[6] = (short)f2bf_u(v1.z); aa[7] = (short)f2bf_u(v1.w);
        afr[kt] = aa;
    }
    float pb[4];
    #pragma unroll
    for (int r = 0; r < 4; r++) pb[r] = pwb[otile + g*4 + r];
    const uint16_t* dwb = (const uint16_t*)(ws + OFF_DW);
    int bb = p0 >> 11, mb0 = p0 & (cM - 1);
    float psum[4] = {0,0,0,0}, pssq[4] = {0,0,0,0};
    #pragma unroll
    for (int mt = 0; mt < 4; mt++) {
        const uint16_t* brow = dwb + (size_t)(p0 + mt*16 + ncol) * cCH;
        f32x4 acc = {0.f, 0.f, 0.f, 0.f};
        #pragma unroll
        for (int kt = 0; kt < 6; kt++) {
            short8 bfr = *(const short8*)&brow[kt*32 + g*8];
            acc = __builtin_amdgcn_mfma_f32_16x16x32_bf16(afr[kt], bfr, acc, 0, 0, 0);
        }
        #pragma unroll
        for (int r = 0; r < 4; r++) {
            float e = eluf(acc[r] + pb[r]);
            psum[r] += e; pssq[r] += e*e;
            out[((size_t)bb*cO + otile + g*4 + r)*cM + mb0 + mt*16 + ncol] = e;
        }
    }
    #pragma unroll
    for (int r = 0; r < 4; r++) {
        float s_ = psum[r], q_ = pssq[r];
        #pragma unroll
        for (int off = 1; off < 16; off <<= 1) { s_ += __shfl_xor(s_, off); q_ += __shfl_xor(q_, off); }
        if (ncol == 0) {
            atomicAdd(&red[w*16 + g*4 + r], s_);
            atomicAdd(&red[64 + w*16 + g*4 + r], q_);
        }
    }
    __syncthreads();
    if (t < 64) {
        atomicAdd(&ws[ACC_FIN + blockIdx.y*64 + t], red[t]);
        atomicAdd(&ws[ACC_FIN + 256 + blockIdx.y*64 + t], red[64 + t]);
    }
}

// ---- kK: final BN affine in-place ----
__global__ __launch_bounds__(256) void kK(float* __restrict__ out, const float* __restrict__ ws,
        const float* __restrict__ sepg, const float* __restrict__ sepbe) {
    int i = blockIdx.x * 256 + threadIdx.x;
    if (i < (cB*cO*cM) / 4) {
        int o = (i >> 9) & 255;
        float mn = ws[ACC_FIN + o] * (1.f/16384.f);
        float vr = ws[ACC_FIN + 256 + o] * (1.f/16384.f) - mn*mn;
        float s = sepg[o] * rsqrtf(vr + cEPS);
        float sh = sepbe[o] - mn*s;
        float4 v = ((float4*)out)[i];
        v.x = s*v.x + sh; v.y = s*v.y + sh; v.z = s*v.z + sh; v.w = s*v.w + sh;
        ((float4*)out)[i] = v;
    }
}

extern "C" void kernel_launch(void* const* d_in, const int* in_sizes, int n_in,
                              void* d_out, int out_size, void* d_ws, size_t ws_size,
                              hipStream_t stream) {
    const float* qp   = (const float*)d_in[0];
    const float* sp   = (const float*)d_in[1];
    const float* sf   = (const float*)d_in[2];
    const float* f1w  = (const float*)d_in[3];
    const float* f1b  = (const float*)d_in[4];
    const float* f1g  = (const float*)d_in[5];
    const float* f1be = (const float*)d_in[6];
    const float* f2w  = (const float*)d_in[7];
    const float* f2b  = (const float*)d_in[8];
    const float* f2g  = (const float*)d_in[9];
    const float* f2be = (const float*)d_in[10];
    const float* stw  = (const float*)d_in[11];
    const float* stb  = (const float*)d_in[12];
    const float* stg  = (const float*)d_in[13];
    const float* stbe = (const float*)d_in[14];
    const float* x1w  = (const float*)d_in[15];
    const float* x1b  = (const float*)d_in[16];
    const float* x1g  = (const float*)d_in[17];
    const float* x1be = (const float*)d_in[18];
    const float* x2w  = (const float*)d_in[19];
    const float* x2b  = (const float*)d_in[20];
    const float* x2g  = (const float*)d_in[21];
    const float* x2be = (const float*)d_in[22];
    const float* dww  = (const float*)d_in[23];
    const float* pww  = (const float*)d_in[24];
    const float* pwb  = (const float*)d_in[25];
    const float* sepg = (const float*)d_in[26];
    const float* sepbe= (const float*)d_in[27];
    const int*   nidx = (const int*)d_in[28];
    float* ws  = (float*)d_ws;
    float* out = (float*)d_out;
    if (ws_size < WS_FLOATS * sizeof(float)) return;

    hipMemsetAsync(d_ws, 0, 2304 * sizeof(float), stream);  // zero stat accumulators
    kAT<<<1024 + 4096, 256, 0, stream>>>(qp, sp, f1w, f1b, stw, stb, sf, nidx, ws);
    kCE<<<4096, 256, 0, stream>>>(f1w, f1b, f2w, f2b, f1g, f1be, x1w, x1b, stg, stbe, ws);
    kG<<<NPTS/16, 256, 0, stream>>>(x2w, x2b, x1g, x1be, ws);
    kI<<<NPTS/8,  256, 0, stream>>>(dww, f2g, f2be, x2g, x2be, nidx, ws);
    kJ<<<dim3(NPTS/64, cO/64), 256, 0, stream>>>(pww, pwb, ws, out);
    kK<<<(cB*cO*cM/4 + 255)/256, 256, 0, stream>>>(out, ws, sepg, sepbe);
}

// Round 17
// 212.982 us; speedup vs baseline: 1.2256x; 1.2256x over previous
//
#include <hip/hip_runtime.h>
#include <hip/hip_bf16.h>
#include <cstddef>
#include <cstdint>

constexpr int cB = 8, cN = 8192, cM = 2048, cK = 16, cC = 128, cH = 64, cO = 256, cCH = 192;
constexpr int NPTS = cB * cM;        // 16384
constexpr float cEPS = 1e-5f;

typedef __attribute__((ext_vector_type(8))) short short8;
typedef __attribute__((ext_vector_type(4))) float f32x4;

// ---- workspace layout (float offsets) ----
constexpr size_t ACC_BN1 = 0, ACC_BN2 = 128, ACC_STEM = 256, ACC_X1 = 768, ACC_X2 = 1280, ACC_FIN = 1792;
constexpr size_t OFF_SFT = 8192;                                   // s_feats packed u32(bf16 c, c+64) [B,N,64]
constexpr size_t OFF_H2  = OFF_SFT + (size_t)cB * cN * 64;         // h2 bf16 [pt][64o][16k]
constexpr size_t OFF_TST = OFF_H2 + (size_t)NPTS * 512;            // stem post-ELU bf16 [pt][256]
constexpr size_t OFF_Y1  = OFF_TST + (size_t)NPTS * 128;           // y1 post-ELU bf16 [pt][256]; later DW bf16
constexpr size_t OFF_Y2  = OFF_Y1 + (size_t)NPTS * 256;            // y2 post-ELU bf16 [pt][256] (uses NPTS*128 fl)
constexpr size_t OFF_AL  = OFF_Y2 + (size_t)NPTS * 128;            // aligned coords f32 [pt][48]
constexpr size_t OFF_DW  = OFF_Y1;
constexpr size_t OFF_STWB = OFF_Y2 + (size_t)NPTS * 256;           // stem weights bf16 [256][64] padded (4096 fl)
constexpr size_t OFF_WPB  = OFF_STWB + 4096;                        // W' = f2w*s1 bf16 [64][64] (2048 fl)
constexpr size_t OFF_B2S  = OFF_WPB + 2048;                         // b2s f32 [64]
constexpr size_t WS_FLOATS = OFF_B2S + 64;                          // ~92.3 MB

__device__ __forceinline__ float eluf(float x) { return x > 0.f ? x : __expf(x) - 1.f; }

__device__ __forceinline__ uint32_t pk2bf(float a, float b) {
    uint32_t ua = __float_as_uint(a); ua += 0x7FFFu + ((ua >> 16) & 1u);
    uint32_t ub = __float_as_uint(b); ub += 0x7FFFu + ((ub >> 16) & 1u);
    return (ua >> 16) | (ub & 0xFFFF0000u);
}
__device__ __forceinline__ float bf_lo(uint32_t u) { return __uint_as_float(u << 16); }
__device__ __forceinline__ float bf_hi(uint32_t u) { return __uint_as_float(u & 0xFFFF0000u); }
__device__ __forceinline__ uint16_t f2bf_u(float a) {
    uint32_t ua = __float_as_uint(a); ua += 0x7FFFu + ((ua >> 16) & 1u);
    return (uint16_t)(ua >> 16);
}

#define WAVE_SYNC() do { asm volatile("s_waitcnt lgkmcnt(0)" ::: "memory"); \
                         __builtin_amdgcn_sched_barrier(0); } while (0)

// ---- kS0: stem weights -> bf16 fragment table, zero-padded K 48->64 (one-shot) ----
__global__ __launch_bounds__(256) void kS0(const float* __restrict__ stw, float* __restrict__ ws) {
    int i = blockIdx.x * 256 + threadIdx.x;    // 16384 elements
    uint16_t* stwb = (uint16_t*)(ws + OFF_STWB);
    int o = i >> 6, kk = i & 63;
    stwb[i] = (kk < 48) ? f2bf_u(stw[(size_t)o*48 + kk]) : (uint16_t)0;
}

// ---- kS1: BN1 scale fold -> W' bf16 table + b2s (one-shot, after kAT stats) ----
__global__ __launch_bounds__(256) void kS1(const float* __restrict__ f2w, const float* __restrict__ f2b,
        const float* __restrict__ f1g, const float* __restrict__ f1be, float* __restrict__ ws) {
    __shared__ float s1s[64], sh1s[64];
    int t = threadIdx.x;
    if (t < 64) {
        float mn = ws[ACC_BN1 + t] * (1.f/262144.f);
        float vr = ws[ACC_BN1 + 64 + t] * (1.f/262144.f) - mn*mn;
        float s = f1g[t] * rsqrtf(vr + cEPS);
        s1s[t] = s; sh1s[t] = f1be[t] - mn*s;
    }
    __syncthreads();
    uint16_t* wpb = (uint16_t*)(ws + OFF_WPB);
    for (int i = t; i < 4096; i += 256) {
        int c = i & 63;
        wpb[i] = f2bf_u(f2w[i] * s1s[c]);
    }
    if (t < 64) {
        float a = f2b[t];
        const float* fr = f2w + (size_t)t*64;
        #pragma unroll 8
        for (int c = 0; c < 64; c++) a += fr[c] * sh1s[c];
        ws[OFF_B2S + t] = a;
    }
}

// ==== kAT: j%5==0 -> kA (id=j/5); else -> k_tr (id=j-j/5-1). ====
__global__ __launch_bounds__(256) void kAT(const float* __restrict__ qp, const float* __restrict__ sp,
        const float* __restrict__ f1w, const float* __restrict__ f1b,
        const float* __restrict__ stb,
        const float* __restrict__ sf, const int* __restrict__ nidx, float* __restrict__ ws) {
    __shared__ __align__(16) unsigned char smem[15872];
    int t = threadIdx.x;
    int j = blockIdx.x;
    if (j % 5 != 0) {
        float* tA = (float*)smem;               // [32][33]
        float* tB = (float*)(smem + 4224);      // [32][33]
        int id = j - j / 5 - 1;
        int n0 = (id & 255) * 32, c0 = ((id >> 8) & 1) * 32, b = id >> 9;
        int tx = t & 31, ty = t >> 5;
        #pragma unroll
        for (int jj = 0; jj < 32; jj += 8) {
            tA[(ty + jj)*33 + tx] = sf[((size_t)b * cC + (c0 + ty + jj)) * cN + n0 + tx];
            tB[(ty + jj)*33 + tx] = sf[((size_t)b * cC + 64 + (c0 + ty + jj)) * cN + n0 + tx];
        }
        __syncthreads();
        uint32_t* outp = (uint32_t*)(ws + OFF_SFT);
        #pragma unroll
        for (int jj = 0; jj < 32; jj += 8)
            outp[((size_t)b * cN + (n0 + ty + jj)) * 64 + c0 + tx] =
                pk2bf(tA[tx*33 + ty + jj], tB[tx*33 + ty + jj]);
        return;
    }
    int kaid = j / 5;
    float (*alw)[4][48]   = (float(*)[4][48])smem;             // 3072B
    uint16_t (*albs)[64]  = (uint16_t(*)[64])(smem + 3072);    // 2048B, byte ^= (row&7)<<4
    uint16_t (*tstt)[256] = (uint16_t(*)[256])(smem + 5120);   // 8192B
    float* red            = (float*)(smem + 13312);            // 640 fl
    int lane = t & 63, w = t >> 6;
    int ncol = lane & 15, g = lane >> 4;
    for (int l = t; l < 640; l += 256) red[l] = 0.f;
    __syncthreads();
    const uint16_t* stwb = (const uint16_t*)(ws + OFF_STWB);
    short8 bfr[4][2];
    float sbias[4];
    #pragma unroll
    for (int tt = 0; tt < 4; tt++) {
        int o = w*64 + tt*16 + ncol;
        sbias[tt] = stb[o];
        #pragma unroll
        for (int s = 0; s < 2; s++)
            bfr[tt][s] = *(const short8*)&stwb[(size_t)o*64 + s*32 + g*8];
    }
    float w0 = f1w[lane*3], w1 = f1w[lane*3+1], w2 = f1w[lane*3+2], fb = f1b[lane];
    int pt0 = kaid * 16;
    {
        int p = lane >> 4, k = lane & 15;
        int row = w*4 + p;
        int pt = pt0 + row, b = pt >> 11, m = pt & (cM - 1);
        int id = nidx[(size_t)pt * cK + k];
        #pragma unroll
        for (int c = 0; c < 3; c++) {
            float v = sp[((size_t)b*3 + c)*cN + id] - qp[((size_t)b*3 + c)*cM + m];
            alw[w][p][c*16 + k] = v;
            int bo = ((c*16 + k)*2) ^ ((row & 7) << 4);
            *(uint16_t*)((char*)&albs[row][0] + bo) = f2bf_u(v);
        }
        int bo = ((48 + k)*2) ^ ((row & 7) << 4);
        *(uint16_t*)((char*)&albs[row][0] + bo) = 0;
    }
    WAVE_SYNC();
    {
        float* alg = ws + OFF_AL;
        const float* srcA = &alw[w][0][0];
        int ptw = pt0 + w*4;
        #pragma unroll
        for (int i = 0; i < 3; i++)
            alg[(size_t)ptw*48 + i*64 + lane] = srcA[i*64 + lane];
    }
    float ps1 = 0, pss1 = 0;
    #pragma unroll
    for (int p = 0; p < 4; p++) {
        #pragma unroll
        for (int k = 0; k < 16; k++) {
            float a0 = alw[w][p][k], a1 = alw[w][p][16 + k], a2 = alw[w][p][32 + k];
            float e = eluf(fb + w0*a0 + w1*a1 + w2*a2);
            ps1 += e; pss1 += e*e;
        }
    }
    atomicAdd(&red[512 + lane], ps1); atomicAdd(&red[576 + lane], pss1);
    __syncthreads();
    short8 a0, a1;
    {
        int b0 = (g*16) ^ ((ncol & 7) << 4);
        int b1 = (64 + g*16) ^ ((ncol & 7) << 4);
        a0 = *(const short8*)((const char*)&albs[ncol][0] + b0);
        a1 = *(const short8*)((const char*)&albs[ncol][0] + b1);
    }
    #pragma unroll
    for (int tt = 0; tt < 4; tt++) {
        f32x4 acc = {0.f, 0.f, 0.f, 0.f};
        acc = __builtin_amdgcn_mfma_f32_16x16x32_bf16(a0, bfr[tt][0], acc, 0, 0, 0);
        acc = __builtin_amdgcn_mfma_f32_16x16x32_bf16(a1, bfr[tt][1], acc, 0, 0, 0);
        int o = w*64 + tt*16 + ncol;
        float ps2 = 0, pss2 = 0;
        #pragma unroll
        for (int r = 0; r < 4; r++) {
            float e = eluf(acc[r] + sbias[tt]);
            ps2 += e; pss2 += e*e;
            tstt[g*4 + r][o] = f2bf_u(e);
        }
        atomicAdd(&red[o], ps2); atomicAdd(&red[256 + o], pss2);
    }
    __syncthreads();
    {
        uint4* tst4 = (uint4*)(ws + OFF_TST);
        const uint4* srcT = (const uint4*)&tstt[0][0];
        tst4[(size_t)pt0*32 + t]       = srcT[t];
        tst4[(size_t)pt0*32 + 256 + t] = srcT[256 + t];
    }
    atomicAdd(&ws[ACC_STEM + t], red[t]);
    atomicAdd(&ws[ACC_STEM + 256 + t], red[256 + t]);
    if (t < 64) { atomicAdd(&ws[ACC_BN1 + t], red[512 + t]); atomicAdd(&ws[ACC_BN1 + 64 + t], red[576 + t]); }
}

// ==== kCE: even blocks -> kC (id=j/2, 16 pts), odd -> kE (id=j/2, 16 pts). Round-15 shape,
//      with per-block setup hoisted into kS1 (fragments/bias loaded from tables). ====
__global__ __launch_bounds__(256) void kCE(const float* __restrict__ f1w, const float* __restrict__ f1b,
        const float* __restrict__ x1w, const float* __restrict__ x1b,
        const float* __restrict__ stg, const float* __restrict__ stbe, float* __restrict__ ws) {
    __shared__ __align__(16) unsigned char smem[37120];
    int t = threadIdx.x, lane = t & 63, w = t >> 6;
    int j = blockIdx.x;
    if ((j & 1) == 0) {
        // ---- kC part ----
        int kcid = j >> 1;
        float (*alw)[4][48] = (float(*)[4][48])smem;                      // 3072B
        unsigned char (*h1l)[4][2048] = (unsigned char(*)[4][2048])(smem + 3072);  // 32768B
        float* red  = (float*)(smem + 36608);   // 128 fl
        if (t < 128) red[t] = 0.f;
        __syncthreads();
        float w0 = f1w[lane*3], w1 = f1w[lane*3+1], w2 = f1w[lane*3+2], fb = f1b[lane];
        int ncol = lane & 15, g = lane >> 4;
        const uint16_t* wpb = (const uint16_t*)(ws + OFF_WPB);
        short8 bfr[4][2];
        float bias2[4];
        #pragma unroll
        for (int tt = 0; tt < 4; tt++) {
            int o = tt*16 + ncol;
            bias2[tt] = ws[OFF_B2S + o];
            #pragma unroll
            for (int s = 0; s < 2; s++)
                bfr[tt][s] = *(const short8*)&wpb[(size_t)o*64 + s*32 + g*8];
        }
        int ptw = kcid * 16 + w * 4;
        {
            const float* alg = ws + OFF_AL;
            float* dst = &alw[w][0][0];
            #pragma unroll
            for (int i = 0; i < 3; i++)
                dst[i*64 + lane] = alg[(size_t)ptw*48 + i*64 + lane];
        }
        WAVE_SYNC();
        #pragma unroll
        for (int p = 0; p < 4; p++) {
            #pragma unroll
            for (int k = 0; k < 16; k++) {
                float a0 = alw[w][p][k], a1 = alw[w][p][16 + k], a2 = alw[w][p][32 + k];
                float e = eluf(fb + w0*a0 + w1*a1 + w2*a2);
                int byteoff = (lane*2) ^ ((k & 7) << 4);
                *(uint16_t*)&h1l[w][p][k*128 + byteoff] = (uint16_t)f2bf_u(e);
            }
        }
        WAVE_SYNC();
        float ps[4] = {0,0,0,0}, pss[4] = {0,0,0,0};
        int b0o = (g*16) ^ ((ncol & 7) << 4);
        int b1o = (64 + g*16) ^ ((ncol & 7) << 4);
        short8 a0v[4], a1v[4];
        #pragma unroll
        for (int p = 0; p < 4; p++) {
            a0v[p] = *(const short8*)&h1l[w][p][ncol*128 + b0o];
            a1v[p] = *(const short8*)&h1l[w][p][ncol*128 + b1o];
        }
        WAVE_SYNC();
        uint32_t* h2p = (uint32_t*)(ws + OFF_H2);
        #pragma unroll
        for (int p = 0; p < 4; p++) {
            int pt = ptw + p;
            #pragma unroll
            for (int tt = 0; tt < 4; tt++) {
                f32x4 acc = {0.f, 0.f, 0.f, 0.f};
                acc = __builtin_amdgcn_mfma_f32_16x16x32_bf16(a0v[p], bfr[tt][0], acc, 0, 0, 0);
                acc = __builtin_amdgcn_mfma_f32_16x16x32_bf16(a1v[p], bfr[tt][1], acc, 0, 0, 0);
                float e0 = eluf(acc[0] + bias2[tt]);
                float e1 = eluf(acc[1] + bias2[tt]);
                float e2 = eluf(acc[2] + bias2[tt]);
                float e3 = eluf(acc[3] + bias2[tt]);
                ps[tt]  += e0+e1+e2+e3;
                pss[tt] += e0*e0+e1*e1+e2*e2+e3*e3;
                int o = tt*16 + ncol;
                *(uint2*)(h2p + (size_t)pt*512 + o*8 + g*2) = make_uint2(pk2bf(e0, e1), pk2bf(e2, e3));
            }
        }
        #pragma unroll
        for (int tt = 0; tt < 4; tt++) {
            int o = tt*16 + ncol;
            atomicAdd(&red[o], ps[tt]); atomicAdd(&red[64 + o], pss[tt]);
        }
        __syncthreads();
        if (t < 64) { atomicAdd(&ws[ACC_BN2 + t], red[t]); atomicAdd(&ws[ACC_BN2 + 64 + t], red[64 + t]); }
        return;
    }
    // ---- kE part ----
    {
        int keid = j >> 1;
        float* xw = (float*)smem;                                 // 17408B
        float (*ts)[4][256] = (float(*)[4][256])(smem + 17408);   // 16384B
        float* red = (float*)(smem + 33792);                      // 2048B
        for (int l = t; l < 4096; l += 256) xw[(l >> 4)*17 + (l & 15)] = x1w[l];
        for (int l = t; l < 512; l += 256) red[l] = 0.f;
        float sscl[4], sshf[4];
        #pragma unroll
        for (int i = 0; i < 4; i++) {
            int ch = lane*4 + i;
            float mn = ws[ACC_STEM + ch] * (1.f/16384.f);
            float vr = ws[ACC_STEM + 256 + ch] * (1.f/16384.f) - mn*mn;
            float s = stg[ch] * rsqrtf(vr + cEPS);
            sscl[i] = s; sshf[i] = stbe[ch] - mn*s;
        }
        __syncthreads();
        const uint16_t* tstb = (const uint16_t*)(ws + OFF_TST);
        int pt0 = keid * 16 + w * 4;
        #pragma unroll
        for (int p = 0; p < 4; p++) {
            uint2 v2 = *(const uint2*)&tstb[(size_t)(pt0 + p)*256 + lane*4];
            ts[w][p][lane*4+0] = sscl[0]*bf_lo(v2.x) + sshf[0];
            ts[w][p][lane*4+1] = sscl[1]*bf_hi(v2.x) + sshf[1];
            ts[w][p][lane*4+2] = sscl[2]*bf_lo(v2.y) + sshf[2];
            ts[w][p][lane*4+3] = sscl[3]*bf_hi(v2.y) + sshf[3];
        }
        WAVE_SYNC();
        float eo[4][4];
        #pragma unroll
        for (int sl = 0; sl < 4; sl++) {
            int o = (sl < 2) ? (lane*2 + sl) : (128 + lane*2 + sl - 2);
            int gg = o >> 4;
            float bia = x1b[o];
            float a0 = bia, a1 = bia, a2 = bia, a3 = bia;
            #pragma unroll
            for (int j4 = 0; j4 < 4; j4++) {
                float s0 = xw[o*17 + j4*4], s1 = xw[o*17 + j4*4+1], s2 = xw[o*17 + j4*4+2], s3 = xw[o*17 + j4*4+3];
                float4 t0 = *(const float4*)&ts[w][0][gg*16 + j4*4];
                float4 t1 = *(const float4*)&ts[w][1][gg*16 + j4*4];
                float4 t2 = *(const float4*)&ts[w][2][gg*16 + j4*4];
                float4 t3 = *(const float4*)&ts[w][3][gg*16 + j4*4];
                a0 += s0*t0.x + s1*t0.y + s2*t0.z + s3*t0.w;
                a1 += s0*t1.x + s1*t1.y + s2*t1.z + s3*t1.w;
                a2 += s0*t2.x + s1*t2.y + s2*t2.z + s3*t2.w;
                a3 += s0*t3.x + s1*t3.y + s2*t3.z + s3*t3.w;
            }
            eo[0][sl] = eluf(a0); eo[1][sl] = eluf(a1); eo[2][sl] = eluf(a2); eo[3][sl] = eluf(a3);
            float ps = eo[0][sl]+eo[1][sl]+eo[2][sl]+eo[3][sl];
            float qs = eo[0][sl]*eo[0][sl]+eo[1][sl]*eo[1][sl]+eo[2][sl]*eo[2][sl]+eo[3][sl]*eo[3][sl];
            atomicAdd(&red[o], ps); atomicAdd(&red[256 + o], qs);
        }
        uint32_t* y1p = (uint32_t*)(ws + OFF_Y1);
        #pragma unroll
        for (int p = 0; p < 4; p++) {
            y1p[(size_t)(pt0 + p)*128 + lane]      = pk2bf(eo[p][0], eo[p][1]);
            y1p[(size_t)(pt0 + p)*128 + 64 + lane] = pk2bf(eo[p][2], eo[p][3]);
        }
        __syncthreads();
        atomicAdd(&ws[ACC_X1 + t], red[t]); atomicAdd(&ws[ACC_X1 + 256 + t], red[256 + t]);
    }
}

// ---- kG: y1 bf16 (BN_x1 inline, transposed stage) -> grouped conv x2 -> y2 bf16 + x2 stats ----
__global__ __launch_bounds__(256) void kG(const float* __restrict__ x2w, const float* __restrict__ x2b,
        const float* __restrict__ x1g, const float* __restrict__ x1be, float* __restrict__ ws) {
    __shared__ float xw[256 * 17];
    __shared__ float ts[4][4][256];
    __shared__ float red[512];
    int t = threadIdx.x, lane = t & 63, w = t >> 6;
    for (int l = t; l < 4096; l += 256) xw[(l >> 4)*17 + (l & 15)] = x2w[l];
    for (int l = t; l < 512; l += 256) red[l] = 0.f;
    float sscl[4], sshf[4];
    #pragma unroll
    for (int i = 0; i < 4; i++) {
        int ch = lane*4 + i;
        float mn = ws[ACC_X1 + ch] * (1.f/16384.f);
        float vr = ws[ACC_X1 + 256 + ch] * (1.f/16384.f) - mn*mn;
        float s = x1g[ch] * rsqrtf(vr + cEPS);
        sscl[i] = s; sshf[i] = x1be[ch] - mn*s;
    }
    __syncthreads();
    const uint32_t* y1p = (const uint32_t*)(ws + OFF_Y1);
    int pt0 = blockIdx.x * 16 + w * 4;
    #pragma unroll
    for (int p = 0; p < 4; p++) {
        uint2 v2 = *(const uint2*)(y1p + (size_t)(pt0 + p)*128 + lane*2);
        float vv[4] = { sscl[0]*bf_lo(v2.x) + sshf[0], sscl[1]*bf_hi(v2.x) + sshf[1],
                        sscl[2]*bf_lo(v2.y) + sshf[2], sscl[3]*bf_hi(v2.y) + sshf[3] };
        #pragma unroll
        for (int i = 0; i < 4; i++) {
            int ch = lane*4 + i;
            ts[w][p][((ch & 15) << 4) | (ch >> 4)] = vv[i];
        }
    }
    WAVE_SYNC();
    float eo[4][4];
    #pragma unroll
    for (int sl = 0; sl < 4; sl++) {
        int o = (sl < 2) ? (lane*2 + sl) : (128 + lane*2 + sl - 2);
        int gg = o >> 4;
        float bia = x2b[o];
        float a0 = bia, a1 = bia, a2 = bia, a3 = bia;
        #pragma unroll
        for (int j4 = 0; j4 < 4; j4++) {
            float s0 = xw[o*17 + j4*4], s1 = xw[o*17 + j4*4+1], s2 = xw[o*17 + j4*4+2], s3 = xw[o*17 + j4*4+3];
            float4 t0 = *(const float4*)&ts[w][0][gg*16 + j4*4];
            float4 t1 = *(const float4*)&ts[w][1][gg*16 + j4*4];
            float4 t2 = *(const float4*)&ts[w][2][gg*16 + j4*4];
            float4 t3 = *(const float4*)&ts[w][3][gg*16 + j4*4];
            a0 += s0*t0.x + s1*t0.y + s2*t0.z + s3*t0.w;
            a1 += s0*t1.x + s1*t1.y + s2*t1.z + s3*t1.w;
            a2 += s0*t2.x + s1*t2.y + s2*t2.z + s3*t2.w;
            a3 += s0*t3.x + s1*t3.y + s2*t3.z + s3*t3.w;
        }
        eo[0][sl] = eluf(a0); eo[1][sl] = eluf(a1); eo[2][sl] = eluf(a2); eo[3][sl] = eluf(a3);
        float ps = eo[0][sl]+eo[1][sl]+eo[2][sl]+eo[3][sl];
        float qs = eo[0][sl]*eo[0][sl]+eo[1][sl]*eo[1][sl]+eo[2][sl]*eo[2][sl]+eo[3][sl]*eo[3][sl];
        atomicAdd(&red[o], ps); atomicAdd(&red[256 + o], qs);
    }
    uint32_t* y2p = (uint32_t*)(ws + OFF_Y2);
    #pragma unroll
    for (int p = 0; p < 4; p++) {
        y2p[(size_t)(pt0 + p)*128 + lane]      = pk2bf(eo[p][0], eo[p][1]);
        y2p[(size_t)(pt0 + p)*128 + 64 + lane] = pk2bf(eo[p][2], eo[p][3]);
    }
    __syncthreads();
    atomicAdd(&ws[ACC_X2 + t], red[t]); atomicAdd(&ws[ACC_X2 + 256 + t], red[256 + t]);
}

// ---- kI: wave-per-point gather (packed SFT) + qf + depthwise -> dw (bf16) ----
__global__ __launch_bounds__(256) void kI(const float* __restrict__ dww,
        const float* __restrict__ f2g, const float* __restrict__ f2be,
        const float* __restrict__ x2g, const float* __restrict__ x2be,
        const int* __restrict__ nidx, float* __restrict__ ws) {
    __shared__ float dws[192 * 17];
    __shared__ float xs[4][256];
    const uint32_t* h2p = (const uint32_t*)(ws + OFF_H2);
    const uint32_t* sfp = (const uint32_t*)(ws + OFF_SFT);
    const uint32_t* y2p = (const uint32_t*)(ws + OFF_Y2);
    int t = threadIdx.x, lane = t & 63, w = t >> 6;
    for (int l = t; l < 3072; l += 256) dws[(l >> 4)*17 + (l & 15)] = dww[l];
    float sx[4], shx[4];
    #pragma unroll
    for (int i = 0; i < 4; i++) {
        int ch = lane*4 + i;
        float mn = ws[ACC_X2 + ch] * (1.f/16384.f);
        float vr = ws[ACC_X2 + 256 + ch] * (1.f/16384.f) - mn*mn;
        float s = x2g[ch] * rsqrtf(vr + cEPS);
        sx[i] = s; shx[i] = x2be[ch] - mn*s;
    }
    float s2, sh2;
    {
        float mn = ws[ACC_BN2 + lane] * (1.f/262144.f);
        float vr = ws[ACC_BN2 + 64 + lane] * (1.f/262144.f) - mn*mn;
        s2 = f2g[lane] * rsqrtf(vr + cEPS);
        sh2 = f2be[lane] - mn*s2;
    }
    __syncthreads();
    uint16_t* dwb = (uint16_t*)(ws + OFF_DW);
    int pt0 = blockIdx.x * 8 + w * 2;
    for (int p = 0; p < 2; p++) {
        int pt = pt0 + p, b = pt >> 11;
        const int4* ip = (const int4*)(nidx + (size_t)pt * cK);
        int4 iA = ip[0], iB = ip[1], iC2 = ip[2], iD = ip[3];
        int idxv[16] = {iA.x, iA.y, iA.z, iA.w, iB.x, iB.y, iB.z, iB.w,
                        iC2.x, iC2.y, iC2.z, iC2.w, iD.x, iD.y, iD.z, iD.w};
        float nfa[16], nfb[16];
        #pragma unroll
        for (int k = 0; k < 16; k++) {
            uint32_t u = sfp[((size_t)b*cN + idxv[k]) * 64 + lane];
            nfa[k] = bf_lo(u); nfb[k] = bf_hi(u);
        }
        float nfh[16];
        {
            const uint4* srcq = (const uint4*)(h2p + (size_t)pt*512 + lane*8);
            uint4 ha = srcq[0], hbq = srcq[1];
            nfh[0]  = s2*bf_lo(ha.x)  + sh2; nfh[1]  = s2*bf_hi(ha.x)  + sh2;
            nfh[2]  = s2*bf_lo(ha.y)  + sh2; nfh[3]  = s2*bf_hi(ha.y)  + sh2;
            nfh[4]  = s2*bf_lo(ha.z)  + sh2; nfh[5]  = s2*bf_hi(ha.z)  + sh2;
            nfh[6]  = s2*bf_lo(ha.w)  + sh2; nfh[7]  = s2*bf_hi(ha.w)  + sh2;
            nfh[8]  = s2*bf_lo(hbq.x) + sh2; nfh[9]  = s2*bf_hi(hbq.x) + sh2;
            nfh[10] = s2*bf_lo(hbq.y) + sh2; nfh[11] = s2*bf_hi(hbq.y) + sh2;
            nfh[12] = s2*bf_lo(hbq.z) + sh2; nfh[13] = s2*bf_hi(hbq.z) + sh2;
            nfh[14] = s2*bf_lo(hbq.w) + sh2; nfh[15] = s2*bf_hi(hbq.w) + sh2;
        }
        {
            uint2 v2 = *(const uint2*)(y2p + (size_t)pt*128 + lane*2);
            xs[w][lane*4+0] = sx[0]*bf_lo(v2.x) + shx[0];
            xs[w][lane*4+1] = sx[1]*bf_hi(v2.x) + shx[1];
            xs[w][lane*4+2] = sx[2]*bf_lo(v2.y) + shx[2];
            xs[w][lane*4+3] = sx[3]*bf_hi(v2.y) + shx[3];
        }
        WAVE_SYNC();
        float qc[16];
        #pragma unroll
        for (int l = 0; l < 16; l++) qc[l] = 0.f;
        #pragma unroll
        for (int k = 0; k < 16; k++) {
            float4 x0 = *(const float4*)&xs[w][k*16 + 0];
            float4 x1 = *(const float4*)&xs[w][k*16 + 4];
            float4 x2v = *(const float4*)&xs[w][k*16 + 8];
            float4 x3 = *(const float4*)&xs[w][k*16 + 12];
            float nh = nfh[k];
            qc[0] += nh*x0.x; qc[1] += nh*x0.y; qc[2]  += nh*x0.z; qc[3]  += nh*x0.w;
            qc[4] += nh*x1.x; qc[5] += nh*x1.y; qc[6]  += nh*x1.z; qc[7]  += nh*x1.w;
            qc[8] += nh*x2v.x; qc[9] += nh*x2v.y; qc[10] += nh*x2v.z; qc[11] += nh*x2v.w;
            qc[12] += nh*x3.x; qc[13] += nh*x3.y; qc[14] += nh*x3.z; qc[15] += nh*x3.w;
        }
        float dc = 0;
        #pragma unroll
        for (int l = 0; l < 16; l++) dc += qc[l] * dws[(lane + 128)*17 + l];
        float qa[16], qb[16];
        #pragma unroll
        for (int l = 0; l < 16; l++) { qa[l] = 0.f; qb[l] = 0.f; }
        #pragma unroll
        for (int k = 0; k < 16; k++) {
            float4 x0 = *(const float4*)&xs[w][k*16 + 0];
            float4 x1 = *(const float4*)&xs[w][k*16 + 4];
            float4 x2v = *(const float4*)&xs[w][k*16 + 8];
            float4 x3 = *(const float4*)&xs[w][k*16 + 12];
            float na = nfa[k], nb = nfb[k];
            qa[0] += na*x0.x; qa[1] += na*x0.y; qa[2]  += na*x0.z; qa[3]  += na*x0.w;
            qa[4] += na*x1.x; qa[5] += na*x1.y; qa[6]  += na*x1.z; qa[7]  += na*x1.w;
            qa[8] += na*x2v.x; qa[9] += na*x2v.y; qa[10] += na*x2v.z; qa[11] += na*x2v.w;
            qa[12] += na*x3.x; qa[13] += na*x3.y; qa[14] += na*x3.z; qa[15] += na*x3.w;
            qb[0] += nb*x0.x; qb[1] += nb*x0.y; qb[2]  += nb*x0.z; qb[3]  += nb*x0.w;
            qb[4] += nb*x1.x; qb[5] += nb*x1.y; qb[6]  += nb*x1.z; qb[7]  += nb*x1.w;
            qb[8] += nb*x2v.x; qb[9] += nb*x2v.y; qb[10] += nb*x2v.z; qb[11] += nb*x2v.w;
            qb[12] += nb*x3.x; qb[13] += nb*x3.y; qb[14] += nb*x3.z; qb[15] += nb*x3.w;
        }
        float da = 0, db = 0;
        #pragma unroll
        for (int l = 0; l < 16; l++) {
            da += qa[l] * dws[lane*17 + l];
            db += qb[l] * dws[(lane + 64)*17 + l];
        }
        uint16_t* op = dwb + (size_t)pt * cCH;
        op[lane] = f2bf_u(da); op[lane + 64] = f2bf_u(db); op[lane + 128] = f2bf_u(dc);
        WAVE_SYNC();
    }
}

// ---- kJ: MFMA GEMM out[o][m] = pww[o][c] . dw[m][c] + bias, ELU, stats ----
__global__ __launch_bounds__(256) void kJ(const float* __restrict__ pww, const float* __restrict__ pwb,
                                          float* __restrict__ ws, float* __restrict__ out) {
    __shared__ float red[128];
    int t = threadIdx.x, lane = t & 63, w = t >> 6;
    int ncol = lane & 15, g = lane >> 4;
    if (t < 128) red[t] = 0.f;
    __syncthreads();
    int p0 = blockIdx.x * 64;
    int otile = blockIdx.y * 64 + w * 16;
    short8 afr[6];
    #pragma unroll
    for (int kt = 0; kt < 6; kt++) {
        const float* src = pww + (size_t)(otile + ncol) * cCH + kt*32 + g*8;
        float4 v0 = *(const float4*)src;
        float4 v1 = *(const float4*)(src + 4);
        short8 aa;
        aa[0] = (short)f2bf_u(v0.x); aa[1] = (short)f2bf_u(v0.y);
        aa[2] = (short)f2bf_u(v0.z); aa[3] = (short)f2bf_u(v0.w);
        aa[4] = (short)f2bf_u(v1.x); aa[5] = (short)f2bf_u(v1.y);
        aa[6] = (short)f2bf_u(v1.z); aa[7] = (short)f2bf_u(v1.w);
        afr[kt] = aa;
    }
    float pb[4];
    #pragma unroll
    for (int r = 0; r < 4; r++) pb[r] = pwb[otile + g*4 + r];
    const uint16_t* dwb = (const uint16_t*)(ws + OFF_DW);
    int bb = p0 >> 11, mb0 = p0 & (cM - 1);
    float psum[4] = {0,0,0,0}, pssq[4] = {0,0,0,0};
    #pragma unroll
    for (int mt = 0; mt < 4; mt++) {
        const uint16_t* brow = dwb + (size_t)(p0 + mt*16 + ncol) * cCH;
        f32x4 acc = {0.f, 0.f, 0.f, 0.f};
        #pragma unroll
        for (int kt = 0; kt < 6; kt++) {
            short8 bfr = *(const short8*)&brow[kt*32 + g*8];
            acc = __builtin_amdgcn_mfma_f32_16x16x32_bf16(afr[kt], bfr, acc, 0, 0, 0);
        }
        #pragma unroll
        for (int r = 0; r < 4; r++) {
            float e = eluf(acc[r] + pb[r]);
            psum[r] += e; pssq[r] += e*e;
            out[((size_t)bb*cO + otile + g*4 + r)*cM + mb0 + mt*16 + ncol] = e;
        }
    }
    #pragma unroll
    for (int r = 0; r < 4; r++) {
        float s_ = psum[r], q_ = pssq[r];
        #pragma unroll
        for (int off = 1; off < 16; off <<= 1) { s_ += __shfl_xor(s_, off); q_ += __shfl_xor(q_, off); }
        if (ncol == 0) {
            atomicAdd(&red[w*16 + g*4 + r], s_);
            atomicAdd(&red[64 + w*16 + g*4 + r], q_);
        }
    }
    __syncthreads();
    if (t < 64) {
        atomicAdd(&ws[ACC_FIN + blockIdx.y*64 + t], red[t]);
        atomicAdd(&ws[ACC_FIN + 256 + blockIdx.y*64 + t], red[64 + t]);
    }
}

// ---- kK: final BN affine in-place ----
__global__ __launch_bounds__(256) void kK(float* __restrict__ out, const float* __restrict__ ws,
        const float* __restrict__ sepg, const float* __restrict__ sepbe) {
    int i = blockIdx.x * 256 + threadIdx.x;
    if (i < (cB*cO*cM) / 4) {
        int o = (i >> 9) & 255;
        float mn = ws[ACC_FIN + o] * (1.f/16384.f);
        float vr = ws[ACC_FIN + 256 + o] * (1.f/16384.f) - mn*mn;
        float s = sepg[o] * rsqrtf(vr + cEPS);
        float sh = sepbe[o] - mn*s;
        float4 v = ((float4*)out)[i];
        v.x = s*v.x + sh; v.y = s*v.y + sh; v.z = s*v.z + sh; v.w = s*v.w + sh;
        ((float4*)out)[i] = v;
    }
}

extern "C" void kernel_launch(void* const* d_in, const int* in_sizes, int n_in,
                              void* d_out, int out_size, void* d_ws, size_t ws_size,
                              hipStream_t stream) {
    const float* qp   = (const float*)d_in[0];
    const float* sp   = (const float*)d_in[1];
    const float* sf   = (const float*)d_in[2];
    const float* f1w  = (const float*)d_in[3];
    const float* f1b  = (const float*)d_in[4];
    const float* f1g  = (const float*)d_in[5];
    const float* f1be = (const float*)d_in[6];
    const float* f2w  = (const float*)d_in[7];
    const float* f2b  = (const float*)d_in[8];
    const float* f2g  = (const float*)d_in[9];
    const float* f2be = (const float*)d_in[10];
    const float* stw  = (const float*)d_in[11];
    const float* stb  = (const float*)d_in[12];
    const float* stg  = (const float*)d_in[13];
    const float* stbe = (const float*)d_in[14];
    const float* x1w  = (const float*)d_in[15];
    const float* x1b  = (const float*)d_in[16];
    const float* x1g  = (const float*)d_in[17];
    const float* x1be = (const float*)d_in[18];
    const float* x2w  = (const float*)d_in[19];
    const float* x2b  = (const float*)d_in[20];
    const float* x2g  = (const float*)d_in[21];
    const float* x2be = (const float*)d_in[22];
    const float* dww  = (const float*)d_in[23];
    const float* pww  = (const float*)d_in[24];
    const float* pwb  = (const float*)d_in[25];
    const float* sepg = (const float*)d_in[26];
    const float* sepbe= (const float*)d_in[27];
    const int*   nidx = (const int*)d_in[28];
    float* ws  = (float*)d_ws;
    float* out = (float*)d_out;
    if (ws_size < WS_FLOATS * sizeof(float)) return;

    hipMemsetAsync(d_ws, 0, 2304 * sizeof(float), stream);  // zero stat accumulators
    kS0<<<64, 256, 0, stream>>>(stw, ws);
    kAT<<<1024 + 4096, 256, 0, stream>>>(qp, sp, f1w, f1b, stb, sf, nidx, ws);
    kS1<<<1, 256, 0, stream>>>(f2w, f2b, f1g, f1be, ws);
    kCE<<<2048, 256, 0, stream>>>(f1w, f1b, x1w, x1b, stg, stbe, ws);
    kG<<<NPTS/16, 256, 0, stream>>>(x2w, x2b, x1g, x1be, ws);
    kI<<<NPTS/8,  256, 0, stream>>>(dww, f2g, f2be, x2g, x2be, nidx, ws);
    kJ<<<dim3(NPTS/64, cO/64), 256, 0, stream>>>(pww, pwb, ws, out);
    kK<<<(cB*cO*cM/4 + 255)/256, 256, 0, stream>>>(out, ws, sepg, sepbe);
}

// Round 18
// 210.042 us; speedup vs baseline: 1.2427x; 1.0140x over previous
//
#include <hip/hip_runtime.h>
#include <hip/hip_bf16.h>
#include <cstddef>
#include <cstdint>

constexpr int cB = 8, cN = 8192, cM = 2048, cK = 16, cC = 128, cH = 64, cO = 256, cCH = 192;
constexpr int NPTS = cB * cM;        // 16384
constexpr float cEPS = 1e-5f;

typedef __attribute__((ext_vector_type(8))) short short8;
typedef __attribute__((ext_vector_type(4))) float f32x4;

// ---- workspace layout (float offsets) ----
constexpr size_t ACC_BN1 = 0, ACC_BN2 = 128, ACC_STEM = 256, ACC_X1 = 768, ACC_X2 = 1280, ACC_FIN = 1792;
constexpr size_t OFF_SFT = 8192;                                   // s_feats packed u32(bf16 c, c+64) [B,N,64]
constexpr size_t OFF_H2  = OFF_SFT + (size_t)cB * cN * 64;         // h2 bf16 [pt][64o][16k]
constexpr size_t OFF_TST = OFF_H2 + (size_t)NPTS * 512;            // stem post-ELU bf16 [pt][256]; later OUTB bf16 [NPTS*256]
constexpr size_t OFF_Y1  = OFF_TST + (size_t)NPTS * 128;           // y1 post-ELU bf16 [pt][256]; later DW bf16
constexpr size_t OFF_Y2  = OFF_Y1 + (size_t)NPTS * 256;            // y2 post-ELU bf16 [pt][256] (uses NPTS*128 fl)
constexpr size_t OFF_AL  = OFF_Y2 + (size_t)NPTS * 128;            // aligned coords f32 [pt][48]
constexpr size_t OFF_DW  = OFF_Y1;
constexpr size_t OFF_STWB = OFF_Y2 + (size_t)NPTS * 256;           // stem weights bf16 [256][64] padded (4096 fl)
constexpr size_t OFF_WPB  = OFF_STWB + 4096;                        // W' = f2w*s1 bf16 [64][64] (2048 fl)
constexpr size_t OFF_B2S  = OFF_WPB + 2048;                         // b2s f32 [64]
constexpr size_t WS_FLOATS = OFF_B2S + 64;                          // ~92.3 MB

__device__ __forceinline__ float eluf(float x) { return x > 0.f ? x : __expf(x) - 1.f; }

__device__ __forceinline__ uint32_t pk2bf(float a, float b) {
    uint32_t ua = __float_as_uint(a); ua += 0x7FFFu + ((ua >> 16) & 1u);
    uint32_t ub = __float_as_uint(b); ub += 0x7FFFu + ((ub >> 16) & 1u);
    return (ua >> 16) | (ub & 0xFFFF0000u);
}
__device__ __forceinline__ float bf_lo(uint32_t u) { return __uint_as_float(u << 16); }
__device__ __forceinline__ float bf_hi(uint32_t u) { return __uint_as_float(u & 0xFFFF0000u); }
__device__ __forceinline__ uint16_t f2bf_u(float a) {
    uint32_t ua = __float_as_uint(a); ua += 0x7FFFu + ((ua >> 16) & 1u);
    return (uint16_t)(ua >> 16);
}

#define WAVE_SYNC() do { asm volatile("s_waitcnt lgkmcnt(0)" ::: "memory"); \
                         __builtin_amdgcn_sched_barrier(0); } while (0)

// ---- kS0: stem weights -> bf16 fragment table, zero-padded K 48->64 (one-shot) ----
__global__ __launch_bounds__(256) void kS0(const float* __restrict__ stw, float* __restrict__ ws) {
    int i = blockIdx.x * 256 + threadIdx.x;    // 16384 elements
    uint16_t* stwb = (uint16_t*)(ws + OFF_STWB);
    int o = i >> 6, kk = i & 63;
    stwb[i] = (kk < 48) ? f2bf_u(stw[(size_t)o*48 + kk]) : (uint16_t)0;
}

// ---- kS1: BN1 scale fold -> W' bf16 table + b2s (one-shot, after kAT stats) ----
__global__ __launch_bounds__(256) void kS1(const float* __restrict__ f2w, const float* __restrict__ f2b,
        const float* __restrict__ f1g, const float* __restrict__ f1be, float* __restrict__ ws) {
    __shared__ float s1s[64], sh1s[64];
    int t = threadIdx.x;
    if (t < 64) {
        float mn = ws[ACC_BN1 + t] * (1.f/262144.f);
        float vr = ws[ACC_BN1 + 64 + t] * (1.f/262144.f) - mn*mn;
        float s = f1g[t] * rsqrtf(vr + cEPS);
        s1s[t] = s; sh1s[t] = f1be[t] - mn*s;
    }
    __syncthreads();
    uint16_t* wpb = (uint16_t*)(ws + OFF_WPB);
    for (int i = t; i < 4096; i += 256) {
        int c = i & 63;
        wpb[i] = f2bf_u(f2w[i] * s1s[c]);
    }
    if (t < 64) {
        float a = f2b[t];
        const float* fr = f2w + (size_t)t*64;
        #pragma unroll 8
        for (int c = 0; c < 64; c++) a += fr[c] * sh1s[c];
        ws[OFF_B2S + t] = a;
    }
}

// ==== kAT: j%5==0 -> kA (id=j/5); else -> k_tr (id=j-j/5-1). ====
__global__ __launch_bounds__(256) void kAT(const float* __restrict__ qp, const float* __restrict__ sp,
        const float* __restrict__ f1w, const float* __restrict__ f1b,
        const float* __restrict__ stb,
        const float* __restrict__ sf, const int* __restrict__ nidx, float* __restrict__ ws) {
    __shared__ __align__(16) unsigned char smem[15872];
    int t = threadIdx.x;
    int j = blockIdx.x;
    if (j % 5 != 0) {
        float* tA = (float*)smem;               // [32][33]
        float* tB = (float*)(smem + 4224);      // [32][33]
        int id = j - j / 5 - 1;
        int n0 = (id & 255) * 32, c0 = ((id >> 8) & 1) * 32, b = id >> 9;
        int tx = t & 31, ty = t >> 5;
        #pragma unroll
        for (int jj = 0; jj < 32; jj += 8) {
            tA[(ty + jj)*33 + tx] = sf[((size_t)b * cC + (c0 + ty + jj)) * cN + n0 + tx];
            tB[(ty + jj)*33 + tx] = sf[((size_t)b * cC + 64 + (c0 + ty + jj)) * cN + n0 + tx];
        }
        __syncthreads();
        uint32_t* outp = (uint32_t*)(ws + OFF_SFT);
        #pragma unroll
        for (int jj = 0; jj < 32; jj += 8)
            outp[((size_t)b * cN + (n0 + ty + jj)) * 64 + c0 + tx] =
                pk2bf(tA[tx*33 + ty + jj], tB[tx*33 + ty + jj]);
        return;
    }
    int kaid = j / 5;
    float (*alw)[4][48]   = (float(*)[4][48])smem;             // 3072B
    uint16_t (*albs)[64]  = (uint16_t(*)[64])(smem + 3072);    // 2048B, byte ^= (row&7)<<4
    uint16_t (*tstt)[256] = (uint16_t(*)[256])(smem + 5120);   // 8192B
    float* red            = (float*)(smem + 13312);            // 640 fl
    int lane = t & 63, w = t >> 6;
    int ncol = lane & 15, g = lane >> 4;
    for (int l = t; l < 640; l += 256) red[l] = 0.f;
    __syncthreads();
    const uint16_t* stwb = (const uint16_t*)(ws + OFF_STWB);
    short8 bfr[4][2];
    float sbias[4];
    #pragma unroll
    for (int tt = 0; tt < 4; tt++) {
        int o = w*64 + tt*16 + ncol;
        sbias[tt] = stb[o];
        #pragma unroll
        for (int s = 0; s < 2; s++)
            bfr[tt][s] = *(const short8*)&stwb[(size_t)o*64 + s*32 + g*8];
    }
    float w0 = f1w[lane*3], w1 = f1w[lane*3+1], w2 = f1w[lane*3+2], fb = f1b[lane];
    int pt0 = kaid * 16;
    {
        int p = lane >> 4, k = lane & 15;
        int row = w*4 + p;
        int pt = pt0 + row, b = pt >> 11, m = pt & (cM - 1);
        int id = nidx[(size_t)pt * cK + k];
        #pragma unroll
        for (int c = 0; c < 3; c++) {
            float v = sp[((size_t)b*3 + c)*cN + id] - qp[((size_t)b*3 + c)*cM + m];
            alw[w][p][c*16 + k] = v;
            int bo = ((c*16 + k)*2) ^ ((row & 7) << 4);
            *(uint16_t*)((char*)&albs[row][0] + bo) = f2bf_u(v);
        }
        int bo = ((48 + k)*2) ^ ((row & 7) << 4);
        *(uint16_t*)((char*)&albs[row][0] + bo) = 0;
    }
    WAVE_SYNC();
    {
        float* alg = ws + OFF_AL;
        const float* srcA = &alw[w][0][0];
        int ptw = pt0 + w*4;
        #pragma unroll
        for (int i = 0; i < 3; i++)
            alg[(size_t)ptw*48 + i*64 + lane] = srcA[i*64 + lane];
    }
    float ps1 = 0, pss1 = 0;
    #pragma unroll
    for (int p = 0; p < 4; p++) {
        #pragma unroll
        for (int k = 0; k < 16; k++) {
            float a0 = alw[w][p][k], a1 = alw[w][p][16 + k], a2 = alw[w][p][32 + k];
            float e = eluf(fb + w0*a0 + w1*a1 + w2*a2);
            ps1 += e; pss1 += e*e;
        }
    }
    atomicAdd(&red[512 + lane], ps1); atomicAdd(&red[576 + lane], pss1);
    __syncthreads();
    short8 a0, a1;
    {
        int b0 = (g*16) ^ ((ncol & 7) << 4);
        int b1 = (64 + g*16) ^ ((ncol & 7) << 4);
        a0 = *(const short8*)((const char*)&albs[ncol][0] + b0);
        a1 = *(const short8*)((const char*)&albs[ncol][0] + b1);
    }
    #pragma unroll
    for (int tt = 0; tt < 4; tt++) {
        f32x4 acc = {0.f, 0.f, 0.f, 0.f};
        acc = __builtin_amdgcn_mfma_f32_16x16x32_bf16(a0, bfr[tt][0], acc, 0, 0, 0);
        acc = __builtin_amdgcn_mfma_f32_16x16x32_bf16(a1, bfr[tt][1], acc, 0, 0, 0);
        int o = w*64 + tt*16 + ncol;
        float ps2 = 0, pss2 = 0;
        #pragma unroll
        for (int r = 0; r < 4; r++) {
            float e = eluf(acc[r] + sbias[tt]);
            ps2 += e; pss2 += e*e;
            tstt[g*4 + r][o] = f2bf_u(e);
        }
        atomicAdd(&red[o], ps2); atomicAdd(&red[256 + o], pss2);
    }
    __syncthreads();
    {
        uint4* tst4 = (uint4*)(ws + OFF_TST);
        const uint4* srcT = (const uint4*)&tstt[0][0];
        tst4[(size_t)pt0*32 + t]       = srcT[t];
        tst4[(size_t)pt0*32 + 256 + t] = srcT[256 + t];
    }
    atomicAdd(&ws[ACC_STEM + t], red[t]);
    atomicAdd(&ws[ACC_STEM + 256 + t], red[256 + t]);
    if (t < 64) { atomicAdd(&ws[ACC_BN1 + t], red[512 + t]); atomicAdd(&ws[ACC_BN1 + 64 + t], red[576 + t]); }
}

// ==== kCE: even blocks -> kC (id=j/2, 16 pts), odd -> kE (id=j/2, 16 pts). ====
__global__ __launch_bounds__(256) void kCE(const float* __restrict__ f1w, const float* __restrict__ f1b,
        const float* __restrict__ x1w, const float* __restrict__ x1b,
        const float* __restrict__ stg, const float* __restrict__ stbe, float* __restrict__ ws) {
    __shared__ __align__(16) unsigned char smem[37120];
    int t = threadIdx.x, lane = t & 63, w = t >> 6;
    int j = blockIdx.x;
    if ((j & 1) == 0) {
        // ---- kC part ----
        int kcid = j >> 1;
        float (*alw)[4][48] = (float(*)[4][48])smem;                      // 3072B
        unsigned char (*h1l)[4][2048] = (unsigned char(*)[4][2048])(smem + 3072);  // 32768B
        float* red  = (float*)(smem + 36608);   // 128 fl
        if (t < 128) red[t] = 0.f;
        __syncthreads();
        float w0 = f1w[lane*3], w1 = f1w[lane*3+1], w2 = f1w[lane*3+2], fb = f1b[lane];
        int ncol = lane & 15, g = lane >> 4;
        const uint16_t* wpb = (const uint16_t*)(ws + OFF_WPB);
        short8 bfr[4][2];
        float bias2[4];
        #pragma unroll
        for (int tt = 0; tt < 4; tt++) {
            int o = tt*16 + ncol;
            bias2[tt] = ws[OFF_B2S + o];
            #pragma unroll
            for (int s = 0; s < 2; s++)
                bfr[tt][s] = *(const short8*)&wpb[(size_t)o*64 + s*32 + g*8];
        }
        int ptw = kcid * 16 + w * 4;
        {
            const float* alg = ws + OFF_AL;
            float* dst = &alw[w][0][0];
            #pragma unroll
            for (int i = 0; i < 3; i++)
                dst[i*64 + lane] = alg[(size_t)ptw*48 + i*64 + lane];
        }
        WAVE_SYNC();
        #pragma unroll
        for (int p = 0; p < 4; p++) {
            #pragma unroll
            for (int k = 0; k < 16; k++) {
                float a0 = alw[w][p][k], a1 = alw[w][p][16 + k], a2 = alw[w][p][32 + k];
                float e = eluf(fb + w0*a0 + w1*a1 + w2*a2);
                int byteoff = (lane*2) ^ ((k & 7) << 4);
                *(uint16_t*)&h1l[w][p][k*128 + byteoff] = (uint16_t)f2bf_u(e);
            }
        }
        WAVE_SYNC();
        float ps[4] = {0,0,0,0}, pss[4] = {0,0,0,0};
        int b0o = (g*16) ^ ((ncol & 7) << 4);
        int b1o = (64 + g*16) ^ ((ncol & 7) << 4);
        short8 a0v[4], a1v[4];
        #pragma unroll
        for (int p = 0; p < 4; p++) {
            a0v[p] = *(const short8*)&h1l[w][p][ncol*128 + b0o];
            a1v[p] = *(const short8*)&h1l[w][p][ncol*128 + b1o];
        }
        WAVE_SYNC();
        uint32_t* h2p = (uint32_t*)(ws + OFF_H2);
        #pragma unroll
        for (int p = 0; p < 4; p++) {
            int pt = ptw + p;
            #pragma unroll
            for (int tt = 0; tt < 4; tt++) {
                f32x4 acc = {0.f, 0.f, 0.f, 0.f};
                acc = __builtin_amdgcn_mfma_f32_16x16x32_bf16(a0v[p], bfr[tt][0], acc, 0, 0, 0);
                acc = __builtin_amdgcn_mfma_f32_16x16x32_bf16(a1v[p], bfr[tt][1], acc, 0, 0, 0);
                float e0 = eluf(acc[0] + bias2[tt]);
                float e1 = eluf(acc[1] + bias2[tt]);
                float e2 = eluf(acc[2] + bias2[tt]);
                float e3 = eluf(acc[3] + bias2[tt]);
                ps[tt]  += e0+e1+e2+e3;
                pss[tt] += e0*e0+e1*e1+e2*e2+e3*e3;
                int o = tt*16 + ncol;
                *(uint2*)(h2p + (size_t)pt*512 + o*8 + g*2) = make_uint2(pk2bf(e0, e1), pk2bf(e2, e3));
            }
        }
        #pragma unroll
        for (int tt = 0; tt < 4; tt++) {
            int o = tt*16 + ncol;
            atomicAdd(&red[o], ps[tt]); atomicAdd(&red[64 + o], pss[tt]);
        }
        __syncthreads();
        if (t < 64) { atomicAdd(&ws[ACC_BN2 + t], red[t]); atomicAdd(&ws[ACC_BN2 + 64 + t], red[64 + t]); }
        return;
    }
    // ---- kE part ----
    {
        int keid = j >> 1;
        float* xw = (float*)smem;                                 // 17408B
        float (*ts)[4][256] = (float(*)[4][256])(smem + 17408);   // 16384B
        float* red = (float*)(smem + 33792);                      // 2048B
        for (int l = t; l < 4096; l += 256) xw[(l >> 4)*17 + (l & 15)] = x1w[l];
        for (int l = t; l < 512; l += 256) red[l] = 0.f;
        float sscl[4], sshf[4];
        #pragma unroll
        for (int i = 0; i < 4; i++) {
            int ch = lane*4 + i;
            float mn = ws[ACC_STEM + ch] * (1.f/16384.f);
            float vr = ws[ACC_STEM + 256 + ch] * (1.f/16384.f) - mn*mn;
            float s = stg[ch] * rsqrtf(vr + cEPS);
            sscl[i] = s; sshf[i] = stbe[ch] - mn*s;
        }
        __syncthreads();
        const uint16_t* tstb = (const uint16_t*)(ws + OFF_TST);
        int pt0 = keid * 16 + w * 4;
        #pragma unroll
        for (int p = 0; p < 4; p++) {
            uint2 v2 = *(const uint2*)&tstb[(size_t)(pt0 + p)*256 + lane*4];
            ts[w][p][lane*4+0] = sscl[0]*bf_lo(v2.x) + sshf[0];
            ts[w][p][lane*4+1] = sscl[1]*bf_hi(v2.x) + sshf[1];
            ts[w][p][lane*4+2] = sscl[2]*bf_lo(v2.y) + sshf[2];
            ts[w][p][lane*4+3] = sscl[3]*bf_hi(v2.y) + sshf[3];
        }
        WAVE_SYNC();
        float eo[4][4];
        #pragma unroll
        for (int sl = 0; sl < 4; sl++) {
            int o = (sl < 2) ? (lane*2 + sl) : (128 + lane*2 + sl - 2);
            int gg = o >> 4;
            float bia = x1b[o];
            float a0 = bia, a1 = bia, a2 = bia, a3 = bia;
            #pragma unroll
            for (int j4 = 0; j4 < 4; j4++) {
                float s0 = xw[o*17 + j4*4], s1 = xw[o*17 + j4*4+1], s2 = xw[o*17 + j4*4+2], s3 = xw[o*17 + j4*4+3];
                float4 t0 = *(const float4*)&ts[w][0][gg*16 + j4*4];
                float4 t1 = *(const float4*)&ts[w][1][gg*16 + j4*4];
                float4 t2 = *(const float4*)&ts[w][2][gg*16 + j4*4];
                float4 t3 = *(const float4*)&ts[w][3][gg*16 + j4*4];
                a0 += s0*t0.x + s1*t0.y + s2*t0.z + s3*t0.w;
                a1 += s0*t1.x + s1*t1.y + s2*t1.z + s3*t1.w;
                a2 += s0*t2.x + s1*t2.y + s2*t2.z + s3*t2.w;
                a3 += s0*t3.x + s1*t3.y + s2*t3.z + s3*t3.w;
            }
            eo[0][sl] = eluf(a0); eo[1][sl] = eluf(a1); eo[2][sl] = eluf(a2); eo[3][sl] = eluf(a3);
            float ps = eo[0][sl]+eo[1][sl]+eo[2][sl]+eo[3][sl];
            float qs = eo[0][sl]*eo[0][sl]+eo[1][sl]*eo[1][sl]+eo[2][sl]*eo[2][sl]+eo[3][sl]*eo[3][sl];
            atomicAdd(&red[o], ps); atomicAdd(&red[256 + o], qs);
        }
        uint32_t* y1p = (uint32_t*)(ws + OFF_Y1);
        #pragma unroll
        for (int p = 0; p < 4; p++) {
            y1p[(size_t)(pt0 + p)*128 + lane]      = pk2bf(eo[p][0], eo[p][1]);
            y1p[(size_t)(pt0 + p)*128 + 64 + lane] = pk2bf(eo[p][2], eo[p][3]);
        }
        __syncthreads();
        atomicAdd(&ws[ACC_X1 + t], red[t]); atomicAdd(&ws[ACC_X1 + 256 + t], red[256 + t]);
    }
}

// ---- kG: y1 bf16 (BN_x1 inline, transposed stage) -> grouped conv x2 -> y2 bf16 + x2 stats ----
__global__ __launch_bounds__(256) void kG(const float* __restrict__ x2w, const float* __restrict__ x2b,
        const float* __restrict__ x1g, const float* __restrict__ x1be, float* __restrict__ ws) {
    __shared__ float xw[256 * 17];
    __shared__ float ts[4][4][256];
    __shared__ float red[512];
    int t = threadIdx.x, lane = t & 63, w = t >> 6;
    for (int l = t; l < 4096; l += 256) xw[(l >> 4)*17 + (l & 15)] = x2w[l];
    for (int l = t; l < 512; l += 256) red[l] = 0.f;
    float sscl[4], sshf[4];
    #pragma unroll
    for (int i = 0; i < 4; i++) {
        int ch = lane*4 + i;
        float mn = ws[ACC_X1 + ch] * (1.f/16384.f);
        float vr = ws[ACC_X1 + 256 + ch] * (1.f/16384.f) - mn*mn;
        float s = x1g[ch] * rsqrtf(vr + cEPS);
        sscl[i] = s; sshf[i] = x1be[ch] - mn*s;
    }
    __syncthreads();
    const uint32_t* y1p = (const uint32_t*)(ws + OFF_Y1);
    int pt0 = blockIdx.x * 16 + w * 4;
    #pragma unroll
    for (int p = 0; p < 4; p++) {
        uint2 v2 = *(const uint2*)(y1p + (size_t)(pt0 + p)*128 + lane*2);
        float vv[4] = { sscl[0]*bf_lo(v2.x) + sshf[0], sscl[1]*bf_hi(v2.x) + sshf[1],
                        sscl[2]*bf_lo(v2.y) + sshf[2], sscl[3]*bf_hi(v2.y) + sshf[3] };
        #pragma unroll
        for (int i = 0; i < 4; i++) {
            int ch = lane*4 + i;
            ts[w][p][((ch & 15) << 4) | (ch >> 4)] = vv[i];
        }
    }
    WAVE_SYNC();
    float eo[4][4];
    #pragma unroll
    for (int sl = 0; sl < 4; sl++) {
        int o = (sl < 2) ? (lane*2 + sl) : (128 + lane*2 + sl - 2);
        int gg = o >> 4;
        float bia = x2b[o];
        float a0 = bia, a1 = bia, a2 = bia, a3 = bia;
        #pragma unroll
        for (int j4 = 0; j4 < 4; j4++) {
            float s0 = xw[o*17 + j4*4], s1 = xw[o*17 + j4*4+1], s2 = xw[o*17 + j4*4+2], s3 = xw[o*17 + j4*4+3];
            float4 t0 = *(const float4*)&ts[w][0][gg*16 + j4*4];
            float4 t1 = *(const float4*)&ts[w][1][gg*16 + j4*4];
            float4 t2 = *(const float4*)&ts[w][2][gg*16 + j4*4];
            float4 t3 = *(const float4*)&ts[w][3][gg*16 + j4*4];
            a0 += s0*t0.x + s1*t0.y + s2*t0.z + s3*t0.w;
            a1 += s0*t1.x + s1*t1.y + s2*t1.z + s3*t1.w;
            a2 += s0*t2.x + s1*t2.y + s2*t2.z + s3*t2.w;
            a3 += s0*t3.x + s1*t3.y + s2*t3.z + s3*t3.w;
        }
        eo[0][sl] = eluf(a0); eo[1][sl] = eluf(a1); eo[2][sl] = eluf(a2); eo[3][sl] = eluf(a3);
        float ps = eo[0][sl]+eo[1][sl]+eo[2][sl]+eo[3][sl];
        float qs = eo[0][sl]*eo[0][sl]+eo[1][sl]*eo[1][sl]+eo[2][sl]*eo[2][sl]+eo[3][sl]*eo[3][sl];
        atomicAdd(&red[o], ps); atomicAdd(&red[256 + o], qs);
    }
    uint32_t* y2p = (uint32_t*)(ws + OFF_Y2);
    #pragma unroll
    for (int p = 0; p < 4; p++) {
        y2p[(size_t)(pt0 + p)*128 + lane]      = pk2bf(eo[p][0], eo[p][1]);
        y2p[(size_t)(pt0 + p)*128 + 64 + lane] = pk2bf(eo[p][2], eo[p][3]);
    }
    __syncthreads();
    atomicAdd(&ws[ACC_X2 + t], red[t]); atomicAdd(&ws[ACC_X2 + 256 + t], red[256 + t]);
}

// ---- kI v2: fused single-pass qa/qb/qc (xs read once), packed nf channels ----
__global__ __launch_bounds__(256) void kI(const float* __restrict__ dww,
        const float* __restrict__ f2g, const float* __restrict__ f2be,
        const float* __restrict__ x2g, const float* __restrict__ x2be,
        const int* __restrict__ nidx, float* __restrict__ ws) {
    __shared__ float dws[192 * 17];
    __shared__ float xs[4][256];
    const uint32_t* h2p = (const uint32_t*)(ws + OFF_H2);
    const uint32_t* sfp = (const uint32_t*)(ws + OFF_SFT);
    const uint32_t* y2p = (const uint32_t*)(ws + OFF_Y2);
    int t = threadIdx.x, lane = t & 63, w = t >> 6;
    for (int l = t; l < 3072; l += 256) dws[(l >> 4)*17 + (l & 15)] = dww[l];
    float sx[4], shx[4];
    #pragma unroll
    for (int i = 0; i < 4; i++) {
        int ch = lane*4 + i;
        float mn = ws[ACC_X2 + ch] * (1.f/16384.f);
        float vr = ws[ACC_X2 + 256 + ch] * (1.f/16384.f) - mn*mn;
        float s = x2g[ch] * rsqrtf(vr + cEPS);
        sx[i] = s; shx[i] = x2be[ch] - mn*s;
    }
    float s2, sh2;
    {
        float mn = ws[ACC_BN2 + lane] * (1.f/262144.f);
        float vr = ws[ACC_BN2 + 64 + lane] * (1.f/262144.f) - mn*mn;
        s2 = f2g[lane] * rsqrtf(vr + cEPS);
        sh2 = f2be[lane] - mn*s2;
    }
    __syncthreads();
    uint16_t* dwb = (uint16_t*)(ws + OFF_DW);
    int pt0 = blockIdx.x * 8 + w * 2;
    for (int p = 0; p < 2; p++) {
        int pt = pt0 + p, b = pt >> 11;
        const int4* ip = (const int4*)(nidx + (size_t)pt * cK);
        int4 iA = ip[0], iB = ip[1], iC2 = ip[2], iD = ip[3];
        int idxv[16] = {iA.x, iA.y, iA.z, iA.w, iB.x, iB.y, iB.z, iB.w,
                        iC2.x, iC2.y, iC2.z, iC2.w, iD.x, iD.y, iD.z, iD.w};
        // gather packed (c=lane, c=lane+64) pairs -> keep PACKED (16 VGPR)
        uint32_t nfp[16];
        #pragma unroll
        for (int k = 0; k < 16; k++)
            nfp[k] = sfp[((size_t)b*cN + idxv[k]) * 64 + lane];
        // h2 channel (lane+128) with BN2 affine -> f32 (16 VGPR)
        float nfh[16];
        {
            const uint4* srcq = (const uint4*)(h2p + (size_t)pt*512 + lane*8);
            uint4 ha = srcq[0], hbq = srcq[1];
            nfh[0]  = s2*bf_lo(ha.x)  + sh2; nfh[1]  = s2*bf_hi(ha.x)  + sh2;
            nfh[2]  = s2*bf_lo(ha.y)  + sh2; nfh[3]  = s2*bf_hi(ha.y)  + sh2;
            nfh[4]  = s2*bf_lo(ha.z)  + sh2; nfh[5]  = s2*bf_hi(ha.z)  + sh2;
            nfh[6]  = s2*bf_lo(ha.w)  + sh2; nfh[7]  = s2*bf_hi(ha.w)  + sh2;
            nfh[8]  = s2*bf_lo(hbq.x) + sh2; nfh[9]  = s2*bf_hi(hbq.x) + sh2;
            nfh[10] = s2*bf_lo(hbq.y) + sh2; nfh[11] = s2*bf_hi(hbq.y) + sh2;
            nfh[12] = s2*bf_lo(hbq.z) + sh2; nfh[13] = s2*bf_hi(hbq.z) + sh2;
            nfh[14] = s2*bf_lo(hbq.w) + sh2; nfh[15] = s2*bf_hi(hbq.w) + sh2;
        }
        {
            uint2 v2 = *(const uint2*)(y2p + (size_t)pt*128 + lane*2);
            xs[w][lane*4+0] = sx[0]*bf_lo(v2.x) + shx[0];
            xs[w][lane*4+1] = sx[1]*bf_hi(v2.x) + shx[1];
            xs[w][lane*4+2] = sx[2]*bf_lo(v2.y) + shx[2];
            xs[w][lane*4+3] = sx[3]*bf_hi(v2.y) + shx[3];
        }
        WAVE_SYNC();
        // fused single pass: xs read ONCE, update qa/qb/qc together
        float qa[16], qb[16], qc[16];
        #pragma unroll
        for (int l = 0; l < 16; l++) { qa[l] = 0.f; qb[l] = 0.f; qc[l] = 0.f; }
        #pragma unroll
        for (int k = 0; k < 16; k++) {
            float4 x0 = *(const float4*)&xs[w][k*16 + 0];
            float4 x1 = *(const float4*)&xs[w][k*16 + 4];
            float4 x2v = *(const float4*)&xs[w][k*16 + 8];
            float4 x3 = *(const float4*)&xs[w][k*16 + 12];
            uint32_t u = nfp[k];
            float na = bf_lo(u), nb = bf_hi(u), nh = nfh[k];
            qa[0] += na*x0.x; qa[1] += na*x0.y; qa[2]  += na*x0.z; qa[3]  += na*x0.w;
            qa[4] += na*x1.x; qa[5] += na*x1.y; qa[6]  += na*x1.z; qa[7]  += na*x1.w;
            qa[8] += na*x2v.x; qa[9] += na*x2v.y; qa[10] += na*x2v.z; qa[11] += na*x2v.w;
            qa[12] += na*x3.x; qa[13] += na*x3.y; qa[14] += na*x3.z; qa[15] += na*x3.w;
            qb[0] += nb*x0.x; qb[1] += nb*x0.y; qb[2]  += nb*x0.z; qb[3]  += nb*x0.w;
            qb[4] += nb*x1.x; qb[5] += nb*x1.y; qb[6]  += nb*x1.z; qb[7]  += nb*x1.w;
            qb[8] += nb*x2v.x; qb[9] += nb*x2v.y; qb[10] += nb*x2v.z; qb[11] += nb*x2v.w;
            qb[12] += nb*x3.x; qb[13] += nb*x3.y; qb[14] += nb*x3.z; qb[15] += nb*x3.w;
            qc[0] += nh*x0.x; qc[1] += nh*x0.y; qc[2]  += nh*x0.z; qc[3]  += nh*x0.w;
            qc[4] += nh*x1.x; qc[5] += nh*x1.y; qc[6]  += nh*x1.z; qc[7]  += nh*x1.w;
            qc[8] += nh*x2v.x; qc[9] += nh*x2v.y; qc[10] += nh*x2v.z; qc[11] += nh*x2v.w;
            qc[12] += nh*x3.x; qc[13] += nh*x3.y; qc[14] += nh*x3.z; qc[15] += nh*x3.w;
        }
        float da = 0, db = 0, dc = 0;
        #pragma unroll
        for (int l = 0; l < 16; l++) {
            da += qa[l] * dws[lane*17 + l];
            db += qb[l] * dws[(lane + 64)*17 + l];
            dc += qc[l] * dws[(lane + 128)*17 + l];
        }
        uint16_t* op = dwb + (size_t)pt * cCH;
        op[lane] = f2bf_u(da); op[lane + 64] = f2bf_u(db); op[lane + 128] = f2bf_u(dc);
        WAVE_SYNC();
    }
}

// ---- kJ: MFMA GEMM, write PRE-BN out as bf16 into dead TST region + stats ----
__global__ __launch_bounds__(256) void kJ(const float* __restrict__ pww, const float* __restrict__ pwb,
                                          float* __restrict__ ws) {
    __shared__ float red[128];
    int t = threadIdx.x, lane = t & 63, w = t >> 6;
    int ncol = lane & 15, g = lane >> 4;
    if (t < 128) red[t] = 0.f;
    __syncthreads();
    int p0 = blockIdx.x * 64;
    int otile = blockIdx.y * 64 + w * 16;
    short8 afr[6];
    #pragma unroll
    for (int kt = 0; kt < 6; kt++) {
        const float* src = pww + (size_t)(otile + ncol) * cCH + kt*32 + g*8;
        float4 v0 = *(const float4*)src;
        float4 v1 = *(const float4*)(src + 4);
        short8 aa;
        aa[0] = (short)f2bf_u(v0.x); aa[1] = (short)f2bf_u(v0.y);
        aa[2] = (short)f2bf_u(v0.z); aa[3] = (short)f2bf_u(v0.w);
        aa[4] = (short)f2bf_u(v1.x); aa[5] = (short)f2bf_u(v1.y);
        aa[6] = (short)f2bf_u(v1.z); aa[7] = (short)f2bf_u(v1.w);
        afr[kt] = aa;
    }
    float pb[4];
    #pragma unroll
    for (int r = 0; r < 4; r++) pb[r] = pwb[otile + g*4 + r];
    const uint16_t* dwb = (const uint16_t*)(ws + OFF_DW);
    uint16_t* outb = (uint16_t*)(ws + OFF_TST);
    int bb = p0 >> 11, mb0 = p0 & (cM - 1);
    float psum[4] = {0,0,0,0}, pssq[4] = {0,0,0,0};
    #pragma unroll
    for (int mt = 0; mt < 4; mt++) {
        const uint16_t* brow = dwb + (size_t)(p0 + mt*16 + ncol) * cCH;
        f32x4 acc = {0.f, 0.f, 0.f, 0.f};
        #pragma unroll
        for (int kt = 0; kt < 6; kt++) {
            short8 bfr = *(const short8*)&brow[kt*32 + g*8];
            acc = __builtin_amdgcn_mfma_f32_16x16x32_bf16(afr[kt], bfr, acc, 0, 0, 0);
        }
        #pragma unroll
        for (int r = 0; r < 4; r++) {
            float e = eluf(acc[r] + pb[r]);
            psum[r] += e; pssq[r] += e*e;
            outb[((size_t)bb*cO + otile + g*4 + r)*cM + mb0 + mt*16 + ncol] = f2bf_u(e);
        }
    }
    #pragma unroll
    for (int r = 0; r < 4; r++) {
        float s_ = psum[r], q_ = pssq[r];
        #pragma unroll
        for (int off = 1; off < 16; off <<= 1) { s_ += __shfl_xor(s_, off); q_ += __shfl_xor(q_, off); }
        if (ncol == 0) {
            atomicAdd(&red[w*16 + g*4 + r], s_);
            atomicAdd(&red[64 + w*16 + g*4 + r], q_);
        }
    }
    __syncthreads();
    if (t < 64) {
        atomicAdd(&ws[ACC_FIN + blockIdx.y*64 + t], red[t]);
        atomicAdd(&ws[ACC_FIN + 256 + blockIdx.y*64 + t], red[64 + t]);
    }
}

// ---- kK: read bf16 pre-BN, apply final BN affine, write f32 out ----
__global__ __launch_bounds__(256) void kK(float* __restrict__ out, const float* __restrict__ ws,
        const float* __restrict__ sepg, const float* __restrict__ sepbe) {
    int i = blockIdx.x * 256 + threadIdx.x;
    if (i < (cB*cO*cM) / 4) {
        int o = (i >> 9) & 255;
        float mn = ws[ACC_FIN + o] * (1.f/16384.f);
        float vr = ws[ACC_FIN + 256 + o] * (1.f/16384.f) - mn*mn;
        float s = sepg[o] * rsqrtf(vr + cEPS);
        float sh = sepbe[o] - mn*s;
        const uint32_t* outb = (const uint32_t*)(ws + OFF_TST);
        uint2 v2 = *(const uint2*)(outb + i*2);
        float4 v;
        v.x = s*bf_lo(v2.x) + sh; v.y = s*bf_hi(v2.x) + sh;
        v.z = s*bf_lo(v2.y) + sh; v.w = s*bf_hi(v2.y) + sh;
        ((float4*)out)[i] = v;
    }
}

extern "C" void kernel_launch(void* const* d_in, const int* in_sizes, int n_in,
                              void* d_out, int out_size, void* d_ws, size_t ws_size,
                              hipStream_t stream) {
    const float* qp   = (const float*)d_in[0];
    const float* sp   = (const float*)d_in[1];
    const float* sf   = (const float*)d_in[2];
    const float* f1w  = (const float*)d_in[3];
    const float* f1b  = (const float*)d_in[4];
    const float* f1g  = (const float*)d_in[5];
    const float* f1be = (const float*)d_in[6];
    const float* f2w  = (const float*)d_in[7];
    const float* f2b  = (const float*)d_in[8];
    const float* f2g  = (const float*)d_in[9];
    const float* f2be = (const float*)d_in[10];
    const float* stw  = (const float*)d_in[11];
    const float* stb  = (const float*)d_in[12];
    const float* stg  = (const float*)d_in[13];
    const float* stbe = (const float*)d_in[14];
    const float* x1w  = (const float*)d_in[15];
    const float* x1b  = (const float*)d_in[16];
    const float* x1g  = (const float*)d_in[17];
    const float* x1be = (const float*)d_in[18];
    const float* x2w  = (const float*)d_in[19];
    const float* x2b  = (const float*)d_in[20];
    const float* x2g  = (const float*)d_in[21];
    const float* x2be = (const float*)d_in[22];
    const float* dww  = (const float*)d_in[23];
    const float* pww  = (const float*)d_in[24];
    const float* pwb  = (const float*)d_in[25];
    const float* sepg = (const float*)d_in[26];
    const float* sepbe= (const float*)d_in[27];
    const int*   nidx = (const int*)d_in[28];
    float* ws  = (float*)d_ws;
    float* out = (float*)d_out;
    if (ws_size < WS_FLOATS * sizeof(float)) return;

    hipMemsetAsync(d_ws, 0, 2304 * sizeof(float), stream);  // zero stat accumulators
    kS0<<<64, 256, 0, stream>>>(stw, ws);
    kAT<<<1024 + 4096, 256, 0, stream>>>(qp, sp, f1w, f1b, stb, sf, nidx, ws);
    kS1<<<1, 256, 0, stream>>>(f2w, f2b, f1g, f1be, ws);
    kCE<<<2048, 256, 0, stream>>>(f1w, f1b, x1w, x1b, stg, stbe, ws);
    kG<<<NPTS/16, 256, 0, stream>>>(x2w, x2b, x1g, x1be, ws);
    kI<<<NPTS/8,  256, 0, stream>>>(dww, f2g, f2be, x2g, x2be, nidx, ws);
    kJ<<<dim3(NPTS/64, cO/64), 256, 0, stream>>>(pww, pwb, ws);
    kK<<<(cB*cO*cM/4 + 255)/256, 256, 0, stream>>>(out, ws, sepg, sepbe);
}